// Round 18
// baseline (1786.511 us; speedup 1.0000x reference)
//
#include <hip/hip_runtime.h>
#include <math.h>

#define B_ 128
#define L_ 200
#define D_ 256
#define NT_ 10000
#define NL_ 4
#define BETA1 0.1f

typedef _Float16 f16x8 __attribute__((ext_vector_type(8)));
typedef _Float16 f16x4 __attribute__((ext_vector_type(4)));
typedef float f32x4 __attribute__((ext_vector_type(4)));

struct HL { _Float16 h, l; };
__device__ __forceinline__ HL split2v(float v) {
    HL r;
    r.h = (_Float16)v;
    r.l = (_Float16)(v - (float)r.h);
    return r;
}

__device__ __forceinline__ float getscale(const unsigned int* amax, int i, int extra) {
    float am = fmaxf(__uint_as_float(amax[i]), 1e-30f);
    return scalbnf(1.f, 6 - ilogbf(am) - extra);
}

// ---------------- user l2norm (+ amax zero-init in block 0) ----------------
__global__ void user_norm_kernel(const int* __restrict__ user_id,
                                 const float* __restrict__ user_emb_w,
                                 float* __restrict__ unorm,
                                 unsigned int* __restrict__ amax) {
    int b = blockIdx.x;
    int d = threadIdx.x; // 256
    if (b == 0 && d < 16) amax[d] = 0u;
    int uid = user_id[b];
    float v = user_emb_w[(long)uid * D_ + d];
    float sq = v * v;
    for (int off = 32; off > 0; off >>= 1) sq += __shfl_down(sq, off, 64);
    __shared__ float s[4];
    int wid = d >> 6, lane = d & 63;
    if (lane == 0) s[wid] = sq;
    __syncthreads();
    float n = sqrtf(s[0] + s[1] + s[2] + s[3]);
    n = fmaxf(n, 1e-12f);
    unorm[b * D_ + d] = v / n;
}

// ---------------- enc0 + pop fused; rep-diag ----------------
__global__ void enc0pop_kernel(const int* __restrict__ event_type,
                               const float* __restrict__ E,
                               const float* __restrict__ pope,
                               const float* __restrict__ unorm,
                               float* __restrict__ encF,
                               float* __restrict__ pop_out,
                               unsigned int* __restrict__ amax, int rep) {
    int d = threadIdx.x;           // 256
    float m = 0.f;
    for (int r0 = 0; r0 < rep; r0++)
    for (int bl = blockIdx.x; bl < B_ * L_; bl += gridDim.x) {
        int b = bl / L_;
        int et = event_type[bl];
        float e = E[(long)et * D_ + d];
        float sg = (e > 0.f) ? 1.f : ((e < 0.f) ? -1.f : 0.f);
        float u = unorm[b * D_ + d];
        float v = e + sg * u;
        encF[(long)bl * D_ + d] = v;
        m = fmaxf(m, fabsf(v));
        pop_out[(long)bl * D_ + d] = (et != 0) ? pope[(long)et * D_ + d] : 0.f;
    }
    for (int off = 32; off > 0; off >>= 1) m = fmaxf(m, __shfl_down(m, off, 64));
    __shared__ float sm[4];
    int wid = d >> 6, lane = d & 63;
    if (lane == 0) sm[wid] = m;
    __syncthreads();
    if (d == 0)
        atomicMax(amax, __float_as_uint(fmaxf(fmaxf(sm[0], sm[1]), fmaxf(sm[2], sm[3]))));
}

// ---------------- diag[b,j] = A[idx_j, idx_j] ----------------
__global__ void diag_kernel(const int* __restrict__ event_type,
                            const float* __restrict__ A,
                            float* __restrict__ diag) {
    int i = blockIdx.x * blockDim.x + threadIdx.x;
    if (i >= B_ * L_) return;
    long idx = (long)event_type[i] - 1;
    diag[i] = A[idx * NT_ + idx];
}

// ---------------- adj split: 4 rows/block; rep-diag ----------------
__global__ void adj_split_kernel(const int* __restrict__ event_type,
                                 const float* __restrict__ A,
                                 const float* __restrict__ diag,
                                 _Float16* __restrict__ adjH,
                                 _Float16* __restrict__ adjL, int rep) {
    int b = blockIdx.y;
    int i0 = blockIdx.x * 4;        // 50 blocks x 4 rows
    int j = threadIdx.x;            // 256 threads, j < L_ active
    __shared__ int sidx[L_];
    __shared__ float sdiag[L_];
    if (j < L_) {
        sidx[j]  = event_type[b * L_ + j] - 1;
        sdiag[j] = diag[b * L_ + j];
    }
    __syncthreads();
    if (j >= L_) return;
    float dj = sdiag[j];
    int cj = sidx[j];
    for (int r0 = 0; r0 < rep; r0++)
#pragma unroll
    for (int r = 0; r < 4; r++) {
        int i = i0 + r;
        float v = A[(long)sidx[i] * NT_ + cj] + dj;
        HL s = split2v(v);
        long o = ((long)b * L_ + i) * L_ + j;
        adjH[o] = s.h; adjL[o] = s.l;
    }
}

// ---------------- W^T split ----------------
__global__ void wsplit_kernel(const float* __restrict__ W,
                              _Float16* __restrict__ WTh,
                              _Float16* __restrict__ WTl) {
    int layer = blockIdx.z;
    int k0 = blockIdx.y * 64, n0 = blockIdx.x * 64;
    const float* Wl = W + (long)layer * D_ * D_;
    __shared__ float t[64][65];
    int tid = threadIdx.x;
    for (int i = 0; i < 16; i++) {
        int idx = i * 256 + tid;
        int k = idx >> 6, n = idx & 63;
        t[k][n] = Wl[(long)(k0 + k) * D_ + n0 + n];
    }
    __syncthreads();
    for (int i = 0; i < 16; i++) {
        int idx = i * 256 + tid;
        int n = idx >> 6, k = idx & 63;
        float v = t[k][n];
        long o = (long)layer * D_ * D_ + (long)(n0 + n) * D_ + (k0 + k);
        HL r = split2v(v);
        WTh[o] = r.h; WTl[o] = r.l;
    }
}

// ---------------- E[1:] split: [n][k] f16 h/l ----------------
__global__ void esplit_kernel(const float* __restrict__ E,
                              _Float16* __restrict__ ETh,
                              _Float16* __restrict__ ETl) {
    long f = ((long)blockIdx.x * 256 + threadIdx.x) * 4;
    float4 v = *(const float4*)(E + D_ + f);
    f16x4 h, l;
    HL r0 = split2v(v.x); h[0] = r0.h; l[0] = r0.l;
    HL r1 = split2v(v.y); h[1] = r1.h; l[1] = r1.l;
    HL r2 = split2v(v.z); h[2] = r2.h; l[2] = r2.l;
    HL r3 = split2v(v.w); h[3] = r3.h; l[3] = r3.l;
    *(f16x4*)(ETh + f) = h;
    *(f16x4*)(ETl + f) = l;
}

// ---------------- gemm1 (r16 two-phase B staging); rep-diag ----------------
__global__ __launch_bounds__(256) void gemm1_kernel(
    const _Float16* __restrict__ adjH, const _Float16* __restrict__ adjL,
    const float* __restrict__ encF,
    _Float16* __restrict__ tmpH, _Float16* __restrict__ tmpL,
    const unsigned int* __restrict__ amax, int layer, int rep) {
    int b = blockIdx.z;
    const _Float16* Ah = adjH + (long)b * L_ * L_;
    const _Float16* Al = adjL + (long)b * L_ * L_;
    const float*    Bf = encF + (long)b * L_ * D_;
    int m0 = blockIdx.y * 128, n0 = blockIdx.x * 128;
    int tid = threadIdx.x, lane = tid & 63, wid = tid >> 6;
    int wr = wid >> 1, wc = wid & 1;
    float scale = getscale(amax, layer, 0);

    __shared__ _Float16 sAh[128][40], sAl[128][40];
    __shared__ _Float16 sBh[128][40], sBl[128][40];

    int fr = lane & 15, kb = (lane >> 4) * 8, fq = lane >> 4;

    for (int r0 = 0; r0 < rep; r0++) {
        f32x4 acc[4][4] = {};
        for (int k0 = 0; k0 < L_; k0 += 32) {
            f16x8 vAh[2], vAl[2];
#pragma unroll
            for (int c = 0; c < 2; c++) {
                int idx = c * 256 + tid;
                int row = idx >> 2, kq = (idx & 3) * 8;
                int gk = k0 + kq;
                f16x8 vh = {}, vl = {};
                if (m0 + row < L_ && gk < L_) {
                    long o = (long)(m0 + row) * L_ + gk;
                    vh = *(const f16x8*)(Ah + o);
                    vl = *(const f16x8*)(Al + o);
                }
                vAh[c] = vh; vAl[c] = vl;
            }
            float vv[2][8];
#pragma unroll
            for (int q2 = 0; q2 < 2; q2++) {
                int item = q2 * 256 + tid;
                int n = item & 127;
                int oct = item >> 7;
                int gk0 = k0 + oct * 8;
#pragma unroll
                for (int q = 0; q < 8; q++) {
                    int gk = gk0 + q;
                    vv[q2][q] = (gk < L_) ? Bf[(long)gk * D_ + n0 + n] : 0.f;
                }
            }
#pragma unroll
            for (int c = 0; c < 2; c++) {
                int idx = c * 256 + tid;
                int row = idx >> 2, kq = (idx & 3) * 8;
                *(f16x8*)&sAh[row][kq] = vAh[c];
                *(f16x8*)&sAl[row][kq] = vAl[c];
            }
#pragma unroll
            for (int q2 = 0; q2 < 2; q2++) {
                int item = q2 * 256 + tid;
                int n = item & 127;
                int oct = item >> 7;
                f16x8 h, l;
#pragma unroll
                for (int q = 0; q < 8; q++) {
                    HL r = split2v(vv[q2][q] * scale);
                    h[q] = r.h; l[q] = r.l;
                }
                *(f16x8*)&sBh[n][oct * 8] = h;
                *(f16x8*)&sBl[n][oct * 8] = l;
            }
            __syncthreads();

            f16x8 fbh[4], fbl[4];
#pragma unroll
            for (int n = 0; n < 4; n++) {
                int rB = wc * 64 + n * 16 + fr;
                fbh[n] = *(const f16x8*)&sBh[rB][kb];
                fbl[n] = *(const f16x8*)&sBl[rB][kb];
            }
#pragma unroll
            for (int m = 0; m < 4; m++) {
                int rA = wr * 64 + m * 16 + fr;
                f16x8 fah = *(const f16x8*)&sAh[rA][kb];
                f16x8 fal = *(const f16x8*)&sAl[rA][kb];
#pragma unroll
                for (int n = 0; n < 4; n++) {
                    acc[m][n] = __builtin_amdgcn_mfma_f32_16x16x32_f16(fah, fbh[n], acc[m][n], 0, 0, 0);
                    acc[m][n] = __builtin_amdgcn_mfma_f32_16x16x32_f16(fah, fbl[n], acc[m][n], 0, 0, 0);
                    acc[m][n] = __builtin_amdgcn_mfma_f32_16x16x32_f16(fal, fbh[n], acc[m][n], 0, 0, 0);
                }
            }
            __syncthreads();
        }

        _Float16* Ch = tmpH + (long)b * L_ * D_;
        _Float16* Cl = tmpL + (long)b * L_ * D_;
#pragma unroll
        for (int m = 0; m < 4; m++)
#pragma unroll
            for (int n = 0; n < 4; n++)
#pragma unroll
                for (int r = 0; r < 4; r++) {
                    int row = m0 + wr * 64 + m * 16 + fq * 4 + r;
                    int col = n0 + wc * 64 + n * 16 + fr;
                    if (row < L_) {
                        HL s = split2v(acc[m][n][r]);
                        long o = (long)row * D_ + col;
                        Ch[o] = s.h; Cl[o] = s.l;
                    }
                }
    }
}

// ---------------- gemm2 (r17 two-phase); rep-diag ----------------
__global__ __launch_bounds__(256) void gemm2_kernel(
    const _Float16* __restrict__ Ah, const _Float16* __restrict__ Al,
    const _Float16* __restrict__ Bh, const _Float16* __restrict__ Bl,
    float* __restrict__ Cf, unsigned int* __restrict__ amax, int rep) {
    int m0 = blockIdx.y * 128, n0 = blockIdx.x * 128;
    int tid = threadIdx.x, lane = tid & 63, wid = tid >> 6;
    int wr = wid >> 1, wc = wid & 1;
    __shared__ _Float16 sAh[128][40], sAl[128][40];
    __shared__ _Float16 sBh[128][40], sBl[128][40];
    __shared__ float sRed[4];
    int fr = lane & 15, kb = (lane >> 4) * 8, fq = lane >> 4;

    for (int r0 = 0; r0 < rep; r0++) {
        f32x4 acc[4][4] = {};
        for (int k0 = 0; k0 < D_; k0 += 32) {
            f16x8 vAh[2], vAl[2], vBh[2], vBl[2];
#pragma unroll
            for (int c = 0; c < 2; c++) {
                int idx = c * 256 + tid;
                int row = idx >> 2, kq = (idx & 3) * 8, gk = k0 + kq;
                long oa = (long)(m0 + row) * D_ + gk;
                vAh[c] = *(const f16x8*)(Ah + oa);
                vAl[c] = *(const f16x8*)(Al + oa);
                long ob = (long)(n0 + row) * D_ + gk;
                vBh[c] = *(const f16x8*)(Bh + ob);
                vBl[c] = *(const f16x8*)(Bl + ob);
            }
#pragma unroll
            for (int c = 0; c < 2; c++) {
                int idx = c * 256 + tid;
                int row = idx >> 2, kq = (idx & 3) * 8;
                *(f16x8*)&sAh[row][kq] = vAh[c];
                *(f16x8*)&sAl[row][kq] = vAl[c];
                *(f16x8*)&sBh[row][kq] = vBh[c];
                *(f16x8*)&sBl[row][kq] = vBl[c];
            }
            __syncthreads();
            f16x8 fbh[4], fbl[4];
#pragma unroll
            for (int n = 0; n < 4; n++) {
                int rB = wc * 64 + n * 16 + fr;
                fbh[n] = *(const f16x8*)&sBh[rB][kb];
                fbl[n] = *(const f16x8*)&sBl[rB][kb];
            }
#pragma unroll
            for (int m = 0; m < 4; m++) {
                int rA = wr * 64 + m * 16 + fr;
                f16x8 fah = *(const f16x8*)&sAh[rA][kb];
                f16x8 fal = *(const f16x8*)&sAl[rA][kb];
#pragma unroll
                for (int n = 0; n < 4; n++) {
                    acc[m][n] = __builtin_amdgcn_mfma_f32_16x16x32_f16(fah, fbh[n], acc[m][n], 0, 0, 0);
                    acc[m][n] = __builtin_amdgcn_mfma_f32_16x16x32_f16(fah, fbl[n], acc[m][n], 0, 0, 0);
                    acc[m][n] = __builtin_amdgcn_mfma_f32_16x16x32_f16(fal, fbh[n], acc[m][n], 0, 0, 0);
                }
            }
            __syncthreads();
        }

        float tmax = 0.f;
#pragma unroll
        for (int m = 0; m < 4; m++)
#pragma unroll
            for (int n = 0; n < 4; n++)
#pragma unroll
                for (int r = 0; r < 4; r++) {
                    int row = m0 + wr * 64 + m * 16 + fq * 4 + r;
                    int col = n0 + wc * 64 + n * 16 + fr;
                    float v = acc[m][n][r];
                    v = (v >= 0.f) ? v : 0.01f * v;
                    Cf[(long)row * D_ + col] = v;
                    tmax = fmaxf(tmax, fabsf(v));
                }
        for (int off = 32; off > 0; off >>= 1) tmax = fmaxf(tmax, __shfl_down(tmax, off, 64));
        if (lane == 0) sRed[wid] = tmax;
        __syncthreads();
        if (tid == 0)
            atomicMax(amax, __float_as_uint(fmaxf(fmaxf(sRed[0], sRed[1]), fmaxf(sRed[2], sRed[3]))));
        __syncthreads();
    }
}

// ---------------- mean + ue + uesplit fused; rep-diag ----------------
__global__ __launch_bounds__(1024) void mean_fused_kernel(
    const float* __restrict__ encF,
    const int* __restrict__ event_type,
    const float* __restrict__ pope,
    const unsigned int* __restrict__ amax,
    float* __restrict__ ue,
    _Float16* __restrict__ ueh,
    _Float16* __restrict__ uel, int rep) {
    int b = blockIdx.x, tid = threadIdx.x;
    int c = tid >> 8, d = tid & 255;
    __shared__ float red1[4][256], red2[4][256];
    for (int r0 = 0; r0 < rep; r0++) {
        float s1 = 0.f, s2 = 0.f;
        int l0 = c * 50;
        for (int l = l0; l < l0 + 50; l++) {
            s1 += encF[((long)b * L_ + l) * D_ + d];
            int et = event_type[b * L_ + l];
            s2 += (et != 0) ? pope[(long)et * D_ + d] : 0.f;
        }
        red1[c][d] = s1;
        red2[c][d] = s2;
        __syncthreads();
        if (c == 0) {
            s1 = red1[0][d] + red1[1][d] + red1[2][d] + red1[3][d];
            s2 = red2[0][d] + red2[1][d] + red2[2][d] + red2[3][d];
            float S = 1.f;
            for (int i = 0; i < NL_; i++) S *= getscale(amax, i, 0);
            ue[b * 2 * D_ + d]      = s1 / (float)L_ / S;
            ue[b * 2 * D_ + D_ + d] = s2 * (BETA1 / (float)L_);
            float sc = getscale(amax, NL_, 8);
            HL r = split2v(s1 * sc);
            ueh[b * D_ + d] = r.h;
            uel[b * D_ + d] = r.l;
        }
        __syncthreads();
    }
}

// ---------------- pred (r17 two-phase); rep-diag ----------------
__global__ __launch_bounds__(256) void pred_mfma_kernel(
    const _Float16* __restrict__ Ah, const _Float16* __restrict__ Al,
    const _Float16* __restrict__ Bh, const _Float16* __restrict__ Bl,
    float* __restrict__ Cf, int rep) {
    int n0 = blockIdx.x * 64;
    int tid = threadIdx.x, lane = tid & 63, wid = tid >> 6;
    int wr = wid >> 1, wc = wid & 1;
    __shared__ _Float16 sAh[128][40], sAl[128][40];
    __shared__ _Float16 sBh[64][40], sBl[64][40];
    int fr = lane & 15, kb = (lane >> 4) * 8, fq = lane >> 4;

    for (int r0 = 0; r0 < rep; r0++) {
        f32x4 acc[4][2] = {};
        for (int k0 = 0; k0 < D_; k0 += 32) {
            f16x8 vAh[2], vAl[2], vBh, vBl;
#pragma unroll
            for (int c = 0; c < 2; c++) {
                int idx = c * 256 + tid;
                int row = idx >> 2, kq = (idx & 3) * 8, gk = k0 + kq;
                long oa = (long)row * D_ + gk;
                vAh[c] = *(const f16x8*)(Ah + oa);
                vAl[c] = *(const f16x8*)(Al + oa);
            }
            {
                int row = tid >> 2, kq = (tid & 3) * 8, gk = k0 + kq;
                f16x8 wh = {}, wl = {};
                if (n0 + row < NT_) {
                    long ob = (long)(n0 + row) * D_ + gk;
                    wh = *(const f16x8*)(Bh + ob);
                    wl = *(const f16x8*)(Bl + ob);
                }
                vBh = wh; vBl = wl;
            }
#pragma unroll
            for (int c = 0; c < 2; c++) {
                int idx = c * 256 + tid;
                int row = idx >> 2, kq = (idx & 3) * 8;
                *(f16x8*)&sAh[row][kq] = vAh[c];
                *(f16x8*)&sAl[row][kq] = vAl[c];
            }
            {
                int row = tid >> 2, kq = (tid & 3) * 8;
                *(f16x8*)&sBh[row][kq] = vBh;
                *(f16x8*)&sBl[row][kq] = vBl;
            }
            __syncthreads();
            f16x8 fbh[2], fbl[2];
#pragma unroll
            for (int n = 0; n < 2; n++) {
                int rB = wc * 32 + n * 16 + fr;
                fbh[n] = *(const f16x8*)&sBh[rB][kb];
                fbl[n] = *(const f16x8*)&sBl[rB][kb];
            }
#pragma unroll
            for (int m = 0; m < 4; m++) {
                int rA = wr * 64 + m * 16 + fr;
                f16x8 fah = *(const f16x8*)&sAh[rA][kb];
                f16x8 fal = *(const f16x8*)&sAl[rA][kb];
#pragma unroll
                for (int n = 0; n < 2; n++) {
                    acc[m][n] = __builtin_amdgcn_mfma_f32_16x16x32_f16(fah, fbh[n], acc[m][n], 0, 0, 0);
                    acc[m][n] = __builtin_amdgcn_mfma_f32_16x16x32_f16(fah, fbl[n], acc[m][n], 0, 0, 0);
                    acc[m][n] = __builtin_amdgcn_mfma_f32_16x16x32_f16(fal, fbh[n], acc[m][n], 0, 0, 0);
                }
            }
            __syncthreads();
        }
#pragma unroll
        for (int m = 0; m < 4; m++)
#pragma unroll
            for (int n = 0; n < 2; n++)
#pragma unroll
                for (int r = 0; r < 4; r++) {
                    int row = wr * 64 + m * 16 + fq * 4 + r;
                    int col = n0 + wc * 32 + n * 16 + fr;
                    if (col < NT_)
                        Cf[(long)row * NT_ + col] = acc[m][n][r];
                }
    }
}

// ---------------- norm + tanh fused; rep-diag on read/reduce ----------------
__global__ void normtanh2_kernel(float* __restrict__ pred, int rep) {
    int b = blockIdx.x, t = threadIdx.x; // 1024
    float* row = pred + (long)b * NT_;
    __shared__ float s[16];
    float v[10];
    float inv = 1.f;
    for (int r0 = 0; r0 < rep; r0++) {
        float sq = 0.f;
#pragma unroll
        for (int p = 0; p < 10; p++) {
            int i = p * 1024 + t;
            v[p] = (i < NT_) ? row[i] : 0.f;
            sq += v[p] * v[p];
        }
        for (int off = 32; off > 0; off >>= 1) sq += __shfl_down(sq, off, 64);
        if ((t & 63) == 0) s[t >> 6] = sq;
        __syncthreads();
        float n = 0.f;
        for (int i = 0; i < 16; i++) n += s[i];
        inv = 1.f / fmaxf(sqrtf(n), 1e-5f);
        __syncthreads();
    }
#pragma unroll
    for (int p = 0; p < 10; p++) {
        int i = p * 1024 + t;
        if (i < NT_) row[i] = tanhf(v[p] * inv);
    }
}

// ================= fallback f32 path kernels =================
__global__ void enc0_kernel(const int* __restrict__ event_type,
                            const float* __restrict__ E,
                            const float* __restrict__ unorm,
                            float* __restrict__ encF) {
    int d = threadIdx.x;
    for (int bl = blockIdx.x; bl < B_ * L_; bl += gridDim.x) {
        int b = bl / L_;
        int et = event_type[bl];
        float e = E[(long)et * D_ + d];
        float sg = (e > 0.f) ? 1.f : ((e < 0.f) ? -1.f : 0.f);
        float u = unorm[b * D_ + d];
        encF[(long)bl * D_ + d] = e + sg * u;
    }
}

__global__ void pop_kernel(const int* __restrict__ event_type,
                           const float* __restrict__ pope,
                           float* __restrict__ pop_out) {
    int bl = blockIdx.x;
    int d = threadIdx.x;
    int et = event_type[bl];
    float np = (et != 0) ? 1.0f : 0.0f;
    pop_out[(long)bl * D_ + d] = pope[(long)et * D_ + d] * np;
}

template <bool BT, bool LEAKY>
__global__ void gemm_kernel(const float* __restrict__ A,
                            const float* __restrict__ Bm,
                            float* __restrict__ C,
                            int M, int N, int K, int lda, int ldb, int ldc,
                            long strideA, long strideB, long strideC) {
    int batch = blockIdx.z;
    A  += (long)batch * strideA;
    Bm += (long)batch * strideB;
    C  += (long)batch * strideC;
    const int BM = 64, BN = 64, BK = 16;
    __shared__ float As[BK][BM + 1];
    __shared__ float Bs[BK][BN + 1];
    int tid = threadIdx.x;
    int m0 = blockIdx.y * BM, n0 = blockIdx.x * BN;
    int tx = tid & 15, ty = tid >> 4;
    float acc[4][4] = {};
    for (int k0 = 0; k0 < K; k0 += BK) {
        {
            int m = tid >> 2, kk = (tid & 3) * 4;
            int gm = m0 + m;
#pragma unroll
            for (int q = 0; q < 4; q++) {
                int gk = k0 + kk + q;
                float x = (gm < M && gk < K) ? A[(long)gm * lda + gk] : 0.f;
                As[kk + q][m] = x;
            }
        }
        if (!BT) {
            int kk = tid >> 4, n = (tid & 15) * 4;
            int gk = k0 + kk;
#pragma unroll
            for (int q = 0; q < 4; q++) {
                int gn = n0 + n + q;
                float x = (gk < K && gn < N) ? Bm[(long)gk * ldb + gn] : 0.f;
                Bs[kk][n + q] = x;
            }
        } else {
            int n = tid >> 2, kk = (tid & 3) * 4;
            int gn = n0 + n;
#pragma unroll
            for (int q = 0; q < 4; q++) {
                int gk = k0 + kk + q;
                float x = (gn < N && gk < K) ? Bm[(long)gn * ldb + gk] : 0.f;
                Bs[kk + q][n] = x;
            }
        }
        __syncthreads();
#pragma unroll
        for (int kk = 0; kk < BK; kk++) {
            float a[4], bv[4];
#pragma unroll
            for (int q = 0; q < 4; q++) a[q] = As[kk][ty * 4 + q];
#pragma unroll
            for (int q = 0; q < 4; q++) bv[q] = Bs[kk][tx * 4 + q];
#pragma unroll
            for (int i = 0; i < 4; i++)
#pragma unroll
                for (int j = 0; j < 4; j++)
                    acc[i][j] += a[i] * bv[j];
        }
        __syncthreads();
    }
#pragma unroll
    for (int i = 0; i < 4; i++) {
        int gm = m0 + ty * 4 + i;
        if (gm >= M) continue;
#pragma unroll
        for (int j = 0; j < 4; j++) {
            int gn = n0 + tx * 4 + j;
            if (gn >= N) continue;
            float v = acc[i][j];
            if (LEAKY) v = (v >= 0.f) ? v : 0.01f * v;
            C[(long)gm * ldc + gn] = v;
        }
    }
}

__global__ void mean_plain_kernel(const float* __restrict__ enc,
                                  const int* __restrict__ event_type,
                                  const float* __restrict__ pope,
                                  float* __restrict__ ue) {
    int b = blockIdx.x, d = threadIdx.x;
    float s1 = 0.f, s2 = 0.f;
    for (int l = 0; l < L_; l++) {
        s1 += enc[((long)b * L_ + l) * D_ + d];
        int et = event_type[b * L_ + l];
        float np = (et != 0) ? 1.0f : 0.0f;
        s2 += pope[(long)et * D_ + d] * np;
    }
    ue[b * (2 * D_) + d]      = s1 / (float)L_;
    ue[b * (2 * D_) + D_ + d] = (s2 / (float)L_) * BETA1;
}

__global__ void adj_kernel_f32(const int* __restrict__ event_type,
                               const float* __restrict__ A,
                               const float* __restrict__ diag,
                               float* __restrict__ adj) {
    int b = blockIdx.y;
    int i = blockIdx.x;
    int j = threadIdx.x;
    __shared__ int sidx[L_];
    __shared__ float sdiag[L_];
    if (j < L_) {
        sidx[j]  = event_type[b * L_ + j] - 1;
        sdiag[j] = diag[b * L_ + j];
    }
    __syncthreads();
    if (j >= L_) return;
    long row = (long)event_type[b * L_ + i] - 1;
    adj[((long)b * L_ + i) * L_ + j] = A[row * NT_ + sidx[j]] + sdiag[j];
}

__global__ void normtanh_kernel(float* __restrict__ pred) {
    int b = blockIdx.x;
    int t = threadIdx.x;
    float* row = pred + (long)b * NT_;
    float sq = 0.f;
    for (int i = t; i < NT_; i += 256) { float v = row[i]; sq += v * v; }
    for (int off = 32; off > 0; off >>= 1) sq += __shfl_down(sq, off, 64);
    __shared__ float s[4];
    int wid = t >> 6, lane = t & 63;
    if (lane == 0) s[wid] = sq;
    __syncthreads();
    float n = sqrtf(s[0] + s[1] + s[2] + s[3]);
    n = fmaxf(n, 1e-5f);
    float inv = 1.f / n;
    for (int i = t; i < NT_; i += 256) row[i] = tanhf(row[i] * inv);
}

extern "C" void kernel_launch(void* const* d_in, const int* in_sizes, int n_in,
                              void* d_out, int out_size, void* d_ws, size_t ws_size,
                              hipStream_t stream) {
    const int*   user_id    = (const int*)d_in[0];
    const int*   event_type = (const int*)d_in[1];
    const float* A          = (const float*)d_in[2];
    const float* pope       = (const float*)d_in[3];
    const float* E          = (const float*)d_in[4];
    const float* U          = (const float*)d_in[5];
    const float* W          = (const float*)d_in[6];

    float* out  = (float*)d_out;
    float* pred = out;                               // B*NT
    float* ue   = out + (long)B_ * NT_;              // B*2D
    float* pop  = ue  + (long)B_ * 2 * D_;           // B*L*D

    // ---- fast-path workspace carve ----
    char* w = (char*)d_ws;
    auto carve = [&](size_t bytes) { char* p = w; w += (bytes + 255) & ~(size_t)255; return p; };
    unsigned int* amax = (unsigned int*)carve(64);
    _Float16* adjH  = (_Float16*)carve((size_t)B_ * L_ * L_ * 2);
    _Float16* adjL  = (_Float16*)carve((size_t)B_ * L_ * L_ * 2);
    _Float16* tmpH  = (_Float16*)carve((size_t)B_ * L_ * D_ * 2);
    _Float16* tmpL  = (_Float16*)carve((size_t)B_ * L_ * D_ * 2);
    float*    encF  = (float*)carve((size_t)B_ * L_ * D_ * 4);
    _Float16* WTh   = (_Float16*)carve((size_t)NL_ * D_ * D_ * 2);
    _Float16* WTl   = (_Float16*)carve((size_t)NL_ * D_ * D_ * 2);
    _Float16* ETh   = (_Float16*)carve((size_t)NT_ * D_ * 2);
    _Float16* ETl   = (_Float16*)carve((size_t)NT_ * D_ * 2);
    _Float16* ueh   = (_Float16*)carve((size_t)B_ * D_ * 2);
    _Float16* uel   = (_Float16*)carve((size_t)B_ * D_ * 2);
    float*    unorm = (float*)carve((size_t)B_ * D_ * 4);
    float*    diag  = (float*)carve((size_t)B_ * L_ * 4);
    size_t needed = (size_t)(w - (char*)d_ws);

    const int RP = 16;   // diagnostic amplification (idempotent recompute)

    if (ws_size >= needed) {
        // ================= fast path (diagnostic build) =================
        user_norm_kernel<<<B_, 256, 0, stream>>>(user_id, U, unorm, amax);
        enc0pop_kernel<<<1280, 256, 0, stream>>>(event_type, E, pope, unorm, encF, pop, amax, RP);
        diag_kernel<<<(B_ * L_ + 255) / 256, 256, 0, stream>>>(event_type, A, diag);
        adj_split_kernel<<<dim3(50, B_), 256, 0, stream>>>(event_type, A, diag, adjH, adjL, RP);
        wsplit_kernel<<<dim3(4, 4, NL_), 256, 0, stream>>>(W, WTh, WTl);
        esplit_kernel<<<NT_ * D_ / 1024, 256, 0, stream>>>(E, ETh, ETl);

        for (int i = 0; i < NL_; i++) {
            gemm1_kernel<<<dim3(2, 2, B_), 256, 0, stream>>>(
                adjH, adjL, encF, tmpH, tmpL, amax, i, (i == 0) ? RP : 1);
            gemm2_kernel<<<dim3(2, B_ * L_ / 128), 256, 0, stream>>>(
                tmpH, tmpL, WTh + (long)i * D_ * D_, WTl + (long)i * D_ * D_,
                encF, amax + i + 1, (i == 0) ? RP : 1);
        }

        mean_fused_kernel<<<B_, 1024, 0, stream>>>(encF, event_type, pope, amax, ue, ueh, uel, RP);
        pred_mfma_kernel<<<(NT_ + 63) / 64, 256, 0, stream>>>(ueh, uel, ETh, ETl, pred, RP);
        normtanh2_kernel<<<B_, 1024, 0, stream>>>(pred, RP);
    } else {
        // ================= fallback: f32 path =================
        float* ws0   = (float*)d_ws;
        float* uno   = ws0;
        float* dia   = uno + B_ * D_;
        float* adjF  = dia + B_ * L_;
        float* encA2 = adjF + (long)B_ * L_ * L_;
        float* encB2 = encA2 + (long)B_ * L_ * D_;
        float* tmp   = pop;

        user_norm_kernel<<<B_, 256, 0, stream>>>(user_id, U, uno, (unsigned int*)dia);
        enc0_kernel<<<1280, 256, 0, stream>>>(event_type, E, uno, encA2);
        diag_kernel<<<(B_ * L_ + 255) / 256, 256, 0, stream>>>(event_type, A, dia);
        adj_kernel_f32<<<dim3(L_, B_), 256, 0, stream>>>(event_type, A, dia, adjF);

        float* cur = encA2; float* nxt = encB2;
        for (int i = 0; i < NL_; i++) {
            dim3 g1((D_ + 63) / 64, (L_ + 63) / 64, B_);
            gemm_kernel<false, false><<<g1, 256, 0, stream>>>(
                adjF, cur, tmp, L_, D_, L_, L_, D_, D_,
                (long)L_ * L_, (long)L_ * D_, (long)L_ * D_);
            dim3 g2((D_ + 63) / 64, (B_ * L_ + 63) / 64, 1);
            gemm_kernel<false, true><<<g2, 256, 0, stream>>>(
                tmp, W + (long)i * D_ * D_, nxt, B_ * L_, D_, D_, D_, D_, D_, 0, 0, 0);
            float* t = cur; cur = nxt; nxt = t;
        }
        pop_kernel<<<B_ * L_, 256, 0, stream>>>(event_type, pope, pop);
        mean_plain_kernel<<<B_, 256, 0, stream>>>(cur, event_type, pope, ue);

        dim3 g3((NT_ + 63) / 64, (B_ + 63) / 64, 1);
        gemm_kernel<true, false><<<g3, 256, 0, stream>>>(
            ue, E + D_, pred, B_, NT_, D_, 2 * D_, D_, NT_, 0, 0, 0);
        normtanh_kernel<<<B_, 256, 0, stream>>>(pred);
    }
}

// Round 19
// 389.778 us; speedup vs baseline: 4.5834x; 4.5834x over previous
//
#include <hip/hip_runtime.h>
#include <math.h>

#define B_ 128
#define L_ 200
#define D_ 256
#define NT_ 10000
#define NL_ 4
#define BETA1 0.1f

typedef _Float16 f16x8 __attribute__((ext_vector_type(8)));
typedef _Float16 f16x4 __attribute__((ext_vector_type(4)));
typedef float f32x4 __attribute__((ext_vector_type(4)));

struct HL { _Float16 h, l; };
__device__ __forceinline__ HL split2v(float v) {
    HL r;
    r.h = (_Float16)v;
    r.l = (_Float16)(v - (float)r.h);
    return r;
}

__device__ __forceinline__ float getscale(const unsigned int* amax, int i, int extra) {
    float am = fmaxf(__uint_as_float(amax[i]), 1e-30f);
    return scalbnf(1.f, 6 - ilogbf(am) - extra);
}

// ---------------- user l2norm (+ amax zero-init in block 0) ----------------
__global__ void user_norm_kernel(const int* __restrict__ user_id,
                                 const float* __restrict__ user_emb_w,
                                 float* __restrict__ unorm,
                                 unsigned int* __restrict__ amax) {
    int b = blockIdx.x;
    int d = threadIdx.x; // 256
    if (b == 0 && d < 16) amax[d] = 0u;
    int uid = user_id[b];
    float v = user_emb_w[(long)uid * D_ + d];
    float sq = v * v;
    for (int off = 32; off > 0; off >>= 1) sq += __shfl_down(sq, off, 64);
    __shared__ float s[4];
    int wid = d >> 6, lane = d & 63;
    if (lane == 0) s[wid] = sq;
    __syncthreads();
    float n = sqrtf(s[0] + s[1] + s[2] + s[3]);
    n = fmaxf(n, 1e-12f);
    unorm[b * D_ + d] = v / n;
}

// ---------------- enc0 + pop fused; absmax one atomic per block ----------------
__global__ void enc0pop_kernel(const int* __restrict__ event_type,
                               const float* __restrict__ E,
                               const float* __restrict__ pope,
                               const float* __restrict__ unorm,
                               float* __restrict__ encF,
                               float* __restrict__ pop_out,
                               unsigned int* __restrict__ amax) {
    int d = threadIdx.x;           // 256
    float m = 0.f;
    for (int bl = blockIdx.x; bl < B_ * L_; bl += gridDim.x) {
        int b = bl / L_;
        int et = event_type[bl];
        float e = E[(long)et * D_ + d];
        float sg = (e > 0.f) ? 1.f : ((e < 0.f) ? -1.f : 0.f);
        float u = unorm[b * D_ + d];
        float v = e + sg * u;
        encF[(long)bl * D_ + d] = v;
        m = fmaxf(m, fabsf(v));
        pop_out[(long)bl * D_ + d] = (et != 0) ? pope[(long)et * D_ + d] : 0.f;
    }
    for (int off = 32; off > 0; off >>= 1) m = fmaxf(m, __shfl_down(m, off, 64));
    __shared__ float sm[4];
    int wid = d >> 6, lane = d & 63;
    if (lane == 0) sm[wid] = m;
    __syncthreads();
    if (d == 0)
        atomicMax(amax, __float_as_uint(fmaxf(fmaxf(sm[0], sm[1]), fmaxf(sm[2], sm[3]))));
}

// ---------------- diag[b,j] = A[idx_j, idx_j] ----------------
__global__ void diag_kernel(const int* __restrict__ event_type,
                            const float* __restrict__ A,
                            float* __restrict__ diag) {
    int i = blockIdx.x * blockDim.x + threadIdx.x;
    if (i >= B_ * L_) return;
    long idx = (long)event_type[i] - 1;
    diag[i] = A[idx * NT_ + idx];
}

// ---------------- adj split: 4 rows/block (staging amortized, ILP 4) ----------------
__global__ void adj_split_kernel(const int* __restrict__ event_type,
                                 const float* __restrict__ A,
                                 const float* __restrict__ diag,
                                 _Float16* __restrict__ adjH,
                                 _Float16* __restrict__ adjL) {
    int b = blockIdx.y;
    int i0 = blockIdx.x * 4;        // 50 blocks x 4 rows
    int j = threadIdx.x;            // 256 threads, j < L_ active
    __shared__ int sidx[L_];
    __shared__ float sdiag[L_];
    if (j < L_) {
        sidx[j]  = event_type[b * L_ + j] - 1;
        sdiag[j] = diag[b * L_ + j];
    }
    __syncthreads();
    if (j >= L_) return;
    float dj = sdiag[j];
    int cj = sidx[j];
#pragma unroll
    for (int r = 0; r < 4; r++) {
        int i = i0 + r;
        float v = A[(long)sidx[i] * NT_ + cj] + dj;
        HL s = split2v(v);
        long o = ((long)b * L_ + i) * L_ + j;
        adjH[o] = s.h; adjL[o] = s.l;
    }
}

// ---------------- W^T split ----------------
__global__ void wsplit_kernel(const float* __restrict__ W,
                              _Float16* __restrict__ WTh,
                              _Float16* __restrict__ WTl) {
    int layer = blockIdx.z;
    int k0 = blockIdx.y * 64, n0 = blockIdx.x * 64;
    const float* Wl = W + (long)layer * D_ * D_;
    __shared__ float t[64][65];
    int tid = threadIdx.x;
    for (int i = 0; i < 16; i++) {
        int idx = i * 256 + tid;
        int k = idx >> 6, n = idx & 63;
        t[k][n] = Wl[(long)(k0 + k) * D_ + n0 + n];
    }
    __syncthreads();
    for (int i = 0; i < 16; i++) {
        int idx = i * 256 + tid;
        int n = idx >> 6, k = idx & 63;
        float v = t[k][n];
        long o = (long)layer * D_ * D_ + (long)(n0 + n) * D_ + (k0 + k);
        HL r = split2v(v);
        WTh[o] = r.h; WTl[o] = r.l;
    }
}

// ---------------- E[1:] split: [n][k] f16 h/l ----------------
__global__ void esplit_kernel(const float* __restrict__ E,
                              _Float16* __restrict__ ETh,
                              _Float16* __restrict__ ETl) {
    long f = ((long)blockIdx.x * 256 + threadIdx.x) * 4;
    float4 v = *(const float4*)(E + D_ + f);
    f16x4 h, l;
    HL r0 = split2v(v.x); h[0] = r0.h; l[0] = r0.l;
    HL r1 = split2v(v.y); h[1] = r1.h; l[1] = r1.l;
    HL r2 = split2v(v.z); h[2] = r2.h; l[2] = r2.l;
    HL r3 = split2v(v.w); h[3] = r3.h; l[3] = r3.l;
    *(f16x4*)(ETh + f) = h;
    *(f16x4*)(ETl + f) = l;
}

// ---------------- gemm1: tmp = adj @ enc (two-phase B staging; occupancy 4 w/EU) ----
__global__ __launch_bounds__(256, 4) void gemm1_kernel(
    const _Float16* __restrict__ adjH, const _Float16* __restrict__ adjL,
    const float* __restrict__ encF,
    _Float16* __restrict__ tmpH, _Float16* __restrict__ tmpL,
    const unsigned int* __restrict__ amax, int layer) {
    int b = blockIdx.z;
    const _Float16* Ah = adjH + (long)b * L_ * L_;
    const _Float16* Al = adjL + (long)b * L_ * L_;
    const float*    Bf = encF + (long)b * L_ * D_;
    int m0 = blockIdx.y * 128, n0 = blockIdx.x * 128;
    int tid = threadIdx.x, lane = tid & 63, wid = tid >> 6;
    int wr = wid >> 1, wc = wid & 1;
    float scale = getscale(amax, layer, 0);

    __shared__ _Float16 sAh[128][40], sAl[128][40];
    __shared__ _Float16 sBh[128][40], sBl[128][40];

    f32x4 acc[4][4] = {};
    int fr = lane & 15, kb = (lane >> 4) * 8, fq = lane >> 4;

    for (int k0 = 0; k0 < L_; k0 += 32) {
        // ---- phase 1: issue ALL global loads (A 2x16B, B 16 f32) before any convert ----
        f16x8 vAh[2], vAl[2];
#pragma unroll
        for (int c = 0; c < 2; c++) {
            int idx = c * 256 + tid;
            int row = idx >> 2, kq = (idx & 3) * 8;
            int gk = k0 + kq;
            f16x8 vh = {}, vl = {};
            if (m0 + row < L_ && gk < L_) {
                long o = (long)(m0 + row) * L_ + gk;
                vh = *(const f16x8*)(Ah + o);
                vl = *(const f16x8*)(Al + o);
            }
            vAh[c] = vh; vAl[c] = vl;
        }
        float vv[2][8];
#pragma unroll
        for (int q2 = 0; q2 < 2; q2++) {
            int item = q2 * 256 + tid;
            int n = item & 127;
            int oct = item >> 7;          // 0..3
            int gk0 = k0 + oct * 8;
#pragma unroll
            for (int q = 0; q < 8; q++) {
                int gk = gk0 + q;
                vv[q2][q] = (gk < L_) ? Bf[(long)gk * D_ + n0 + n] : 0.f;
            }
        }
        // ---- phase 2: convert + LDS writes ----
#pragma unroll
        for (int c = 0; c < 2; c++) {
            int idx = c * 256 + tid;
            int row = idx >> 2, kq = (idx & 3) * 8;
            *(f16x8*)&sAh[row][kq] = vAh[c];
            *(f16x8*)&sAl[row][kq] = vAl[c];
        }
#pragma unroll
        for (int q2 = 0; q2 < 2; q2++) {
            int item = q2 * 256 + tid;
            int n = item & 127;
            int oct = item >> 7;
            f16x8 h, l;
#pragma unroll
            for (int q = 0; q < 8; q++) {
                HL r = split2v(vv[q2][q] * scale);
                h[q] = r.h; l[q] = r.l;
            }
            *(f16x8*)&sBh[n][oct * 8] = h;
            *(f16x8*)&sBl[n][oct * 8] = l;
        }
        __syncthreads();

        f16x8 fbh[4], fbl[4];
#pragma unroll
        for (int n = 0; n < 4; n++) {
            int rB = wc * 64 + n * 16 + fr;
            fbh[n] = *(const f16x8*)&sBh[rB][kb];
            fbl[n] = *(const f16x8*)&sBl[rB][kb];
        }
#pragma unroll
        for (int m = 0; m < 4; m++) {
            int rA = wr * 64 + m * 16 + fr;
            f16x8 fah = *(const f16x8*)&sAh[rA][kb];
            f16x8 fal = *(const f16x8*)&sAl[rA][kb];
#pragma unroll
            for (int n = 0; n < 4; n++) {
                acc[m][n] = __builtin_amdgcn_mfma_f32_16x16x32_f16(fah, fbh[n], acc[m][n], 0, 0, 0);
                acc[m][n] = __builtin_amdgcn_mfma_f32_16x16x32_f16(fah, fbl[n], acc[m][n], 0, 0, 0);
                acc[m][n] = __builtin_amdgcn_mfma_f32_16x16x32_f16(fal, fbh[n], acc[m][n], 0, 0, 0);
            }
        }
        __syncthreads();
    }

    _Float16* Ch = tmpH + (long)b * L_ * D_;
    _Float16* Cl = tmpL + (long)b * L_ * D_;
#pragma unroll
    for (int m = 0; m < 4; m++)
#pragma unroll
        for (int n = 0; n < 4; n++)
#pragma unroll
            for (int r = 0; r < 4; r++) {
                int row = m0 + wr * 64 + m * 16 + fq * 4 + r;
                int col = n0 + wc * 64 + n * 16 + fr;
                if (row < L_) {
                    HL s = split2v(acc[m][n][r]);
                    long o = (long)row * D_ + col;
                    Ch[o] = s.h; Cl[o] = s.l;
                }
            }
}

// ---------------- gemm2: encF = leaky(tmp @ W), absmax (two-phase staging) -------
__global__ __launch_bounds__(256) void gemm2_kernel(
    const _Float16* __restrict__ Ah, const _Float16* __restrict__ Al,
    const _Float16* __restrict__ Bh, const _Float16* __restrict__ Bl,
    float* __restrict__ Cf, unsigned int* __restrict__ amax) {
    int m0 = blockIdx.y * 128, n0 = blockIdx.x * 128;
    int tid = threadIdx.x, lane = tid & 63, wid = tid >> 6;
    int wr = wid >> 1, wc = wid & 1;
    __shared__ _Float16 sAh[128][40], sAl[128][40];
    __shared__ _Float16 sBh[128][40], sBl[128][40];
    __shared__ float sRed[4];
    f32x4 acc[4][4] = {};
    int fr = lane & 15, kb = (lane >> 4) * 8, fq = lane >> 4;

    for (int k0 = 0; k0 < D_; k0 += 32) {
        // phase 1: all loads
        f16x8 vAh[2], vAl[2], vBh[2], vBl[2];
#pragma unroll
        for (int c = 0; c < 2; c++) {
            int idx = c * 256 + tid;
            int row = idx >> 2, kq = (idx & 3) * 8, gk = k0 + kq;
            long oa = (long)(m0 + row) * D_ + gk;
            vAh[c] = *(const f16x8*)(Ah + oa);
            vAl[c] = *(const f16x8*)(Al + oa);
            long ob = (long)(n0 + row) * D_ + gk;
            vBh[c] = *(const f16x8*)(Bh + ob);
            vBl[c] = *(const f16x8*)(Bl + ob);
        }
        // phase 2: LDS writes
#pragma unroll
        for (int c = 0; c < 2; c++) {
            int idx = c * 256 + tid;
            int row = idx >> 2, kq = (idx & 3) * 8;
            *(f16x8*)&sAh[row][kq] = vAh[c];
            *(f16x8*)&sAl[row][kq] = vAl[c];
            *(f16x8*)&sBh[row][kq] = vBh[c];
            *(f16x8*)&sBl[row][kq] = vBl[c];
        }
        __syncthreads();
        f16x8 fbh[4], fbl[4];
#pragma unroll
        for (int n = 0; n < 4; n++) {
            int rB = wc * 64 + n * 16 + fr;
            fbh[n] = *(const f16x8*)&sBh[rB][kb];
            fbl[n] = *(const f16x8*)&sBl[rB][kb];
        }
#pragma unroll
        for (int m = 0; m < 4; m++) {
            int rA = wr * 64 + m * 16 + fr;
            f16x8 fah = *(const f16x8*)&sAh[rA][kb];
            f16x8 fal = *(const f16x8*)&sAl[rA][kb];
#pragma unroll
            for (int n = 0; n < 4; n++) {
                acc[m][n] = __builtin_amdgcn_mfma_f32_16x16x32_f16(fah, fbh[n], acc[m][n], 0, 0, 0);
                acc[m][n] = __builtin_amdgcn_mfma_f32_16x16x32_f16(fah, fbl[n], acc[m][n], 0, 0, 0);
                acc[m][n] = __builtin_amdgcn_mfma_f32_16x16x32_f16(fal, fbh[n], acc[m][n], 0, 0, 0);
            }
        }
        __syncthreads();
    }

    float tmax = 0.f;
#pragma unroll
    for (int m = 0; m < 4; m++)
#pragma unroll
        for (int n = 0; n < 4; n++)
#pragma unroll
            for (int r = 0; r < 4; r++) {
                int row = m0 + wr * 64 + m * 16 + fq * 4 + r;
                int col = n0 + wc * 64 + n * 16 + fr;
                float v = acc[m][n][r];
                v = (v >= 0.f) ? v : 0.01f * v;
                Cf[(long)row * D_ + col] = v;
                tmax = fmaxf(tmax, fabsf(v));
            }
    for (int off = 32; off > 0; off >>= 1) tmax = fmaxf(tmax, __shfl_down(tmax, off, 64));
    if (lane == 0) sRed[wid] = tmax;
    __syncthreads();
    if (tid == 0)
        atomicMax(amax, __float_as_uint(fmaxf(fmaxf(sRed[0], sRed[1]), fmaxf(sRed[2], sRed[3]))));
}

// ---------------- mean + ue + uesplit fused, 1024 thr (4 l-chunks parallel) -----
__global__ __launch_bounds__(1024) void mean_fused_kernel(
    const float* __restrict__ encF,
    const int* __restrict__ event_type,
    const float* __restrict__ pope,
    const unsigned int* __restrict__ amax,
    float* __restrict__ ue,
    _Float16* __restrict__ ueh,
    _Float16* __restrict__ uel) {
    int b = blockIdx.x, tid = threadIdx.x;
    int c = tid >> 8, d = tid & 255;
    float s1 = 0.f, s2 = 0.f;
    int l0 = c * 50;
    for (int l = l0; l < l0 + 50; l++) {
        s1 += encF[((long)b * L_ + l) * D_ + d];
        int et = event_type[b * L_ + l];
        s2 += (et != 0) ? pope[(long)et * D_ + d] : 0.f;
    }
    __shared__ float red1[4][256], red2[4][256];
    red1[c][d] = s1;
    red2[c][d] = s2;
    __syncthreads();
    if (c == 0) {
        s1 = red1[0][d] + red1[1][d] + red1[2][d] + red1[3][d];
        s2 = red2[0][d] + red2[1][d] + red2[2][d] + red2[3][d];
        float S = 1.f;
        for (int i = 0; i < NL_; i++) S *= getscale(amax, i, 0);
        ue[b * 2 * D_ + d]      = s1 / (float)L_ / S;
        ue[b * 2 * D_ + D_ + d] = s2 * (BETA1 / (float)L_);
        float sc = getscale(amax, NL_, 8);
        HL r = split2v(s1 * sc);
        ueh[b * D_ + d] = r.h;
        uel[b * D_ + d] = r.l;
    }
}

// ---------------- pred = ue_scaled @ E[1:]^T (two-phase staging) ----------------
__global__ __launch_bounds__(256) void pred_mfma_kernel(
    const _Float16* __restrict__ Ah, const _Float16* __restrict__ Al,
    const _Float16* __restrict__ Bh, const _Float16* __restrict__ Bl,
    float* __restrict__ Cf) {
    int n0 = blockIdx.x * 64;
    int tid = threadIdx.x, lane = tid & 63, wid = tid >> 6;
    int wr = wid >> 1, wc = wid & 1;
    __shared__ _Float16 sAh[128][40], sAl[128][40];
    __shared__ _Float16 sBh[64][40], sBl[64][40];
    f32x4 acc[4][2] = {};
    int fr = lane & 15, kb = (lane >> 4) * 8, fq = lane >> 4;

    for (int k0 = 0; k0 < D_; k0 += 32) {
        // phase 1: all loads
        f16x8 vAh[2], vAl[2], vBh, vBl;
#pragma unroll
        for (int c = 0; c < 2; c++) {
            int idx = c * 256 + tid;
            int row = idx >> 2, kq = (idx & 3) * 8, gk = k0 + kq;
            long oa = (long)row * D_ + gk;
            vAh[c] = *(const f16x8*)(Ah + oa);
            vAl[c] = *(const f16x8*)(Al + oa);
        }
        {
            int row = tid >> 2, kq = (tid & 3) * 8, gk = k0 + kq;
            f16x8 wh = {}, wl = {};
            if (n0 + row < NT_) {
                long ob = (long)(n0 + row) * D_ + gk;
                wh = *(const f16x8*)(Bh + ob);
                wl = *(const f16x8*)(Bl + ob);
            }
            vBh = wh; vBl = wl;
        }
        // phase 2: LDS writes
#pragma unroll
        for (int c = 0; c < 2; c++) {
            int idx = c * 256 + tid;
            int row = idx >> 2, kq = (idx & 3) * 8;
            *(f16x8*)&sAh[row][kq] = vAh[c];
            *(f16x8*)&sAl[row][kq] = vAl[c];
        }
        {
            int row = tid >> 2, kq = (tid & 3) * 8;
            *(f16x8*)&sBh[row][kq] = vBh;
            *(f16x8*)&sBl[row][kq] = vBl;
        }
        __syncthreads();
        f16x8 fbh[2], fbl[2];
#pragma unroll
        for (int n = 0; n < 2; n++) {
            int rB = wc * 32 + n * 16 + fr;
            fbh[n] = *(const f16x8*)&sBh[rB][kb];
            fbl[n] = *(const f16x8*)&sBl[rB][kb];
        }
#pragma unroll
        for (int m = 0; m < 4; m++) {
            int rA = wr * 64 + m * 16 + fr;
            f16x8 fah = *(const f16x8*)&sAh[rA][kb];
            f16x8 fal = *(const f16x8*)&sAl[rA][kb];
#pragma unroll
            for (int n = 0; n < 2; n++) {
                acc[m][n] = __builtin_amdgcn_mfma_f32_16x16x32_f16(fah, fbh[n], acc[m][n], 0, 0, 0);
                acc[m][n] = __builtin_amdgcn_mfma_f32_16x16x32_f16(fah, fbl[n], acc[m][n], 0, 0, 0);
                acc[m][n] = __builtin_amdgcn_mfma_f32_16x16x32_f16(fal, fbh[n], acc[m][n], 0, 0, 0);
            }
        }
        __syncthreads();
    }
#pragma unroll
    for (int m = 0; m < 4; m++)
#pragma unroll
        for (int n = 0; n < 2; n++)
#pragma unroll
            for (int r = 0; r < 4; r++) {
                int row = wr * 64 + m * 16 + fq * 4 + r;
                int col = n0 + wc * 32 + n * 16 + fr;
                if (col < NT_)
                    Cf[(long)row * NT_ + col] = acc[m][n][r];
            }
}

// ---------------- norm + tanh fused, row in registers ----------------
__global__ void normtanh2_kernel(float* __restrict__ pred) {
    int b = blockIdx.x, t = threadIdx.x; // 1024
    float* row = pred + (long)b * NT_;
    float v[10];
    float sq = 0.f;
#pragma unroll
    for (int p = 0; p < 10; p++) {
        int i = p * 1024 + t;
        v[p] = (i < NT_) ? row[i] : 0.f;
        sq += v[p] * v[p];
    }
    for (int off = 32; off > 0; off >>= 1) sq += __shfl_down(sq, off, 64);
    __shared__ float s[16];
    if ((t & 63) == 0) s[t >> 6] = sq;
    __syncthreads();
    float n = 0.f;
    for (int i = 0; i < 16; i++) n += s[i];
    float inv = 1.f / fmaxf(sqrtf(n), 1e-5f);
#pragma unroll
    for (int p = 0; p < 10; p++) {
        int i = p * 1024 + t;
        if (i < NT_) row[i] = tanhf(v[p] * inv);
    }
}

// ================= fallback f32 path kernels =================
__global__ void enc0_kernel(const int* __restrict__ event_type,
                            const float* __restrict__ E,
                            const float* __restrict__ unorm,
                            float* __restrict__ encF) {
    int d = threadIdx.x;
    for (int bl = blockIdx.x; bl < B_ * L_; bl += gridDim.x) {
        int b = bl / L_;
        int et = event_type[bl];
        float e = E[(long)et * D_ + d];
        float sg = (e > 0.f) ? 1.f : ((e < 0.f) ? -1.f : 0.f);
        float u = unorm[b * D_ + d];
        encF[(long)bl * D_ + d] = e + sg * u;
    }
}

__global__ void pop_kernel(const int* __restrict__ event_type,
                           const float* __restrict__ pope,
                           float* __restrict__ pop_out) {
    int bl = blockIdx.x;
    int d = threadIdx.x;
    int et = event_type[bl];
    float np = (et != 0) ? 1.0f : 0.0f;
    pop_out[(long)bl * D_ + d] = pope[(long)et * D_ + d] * np;
}

template <bool BT, bool LEAKY>
__global__ void gemm_kernel(const float* __restrict__ A,
                            const float* __restrict__ Bm,
                            float* __restrict__ C,
                            int M, int N, int K, int lda, int ldb, int ldc,
                            long strideA, long strideB, long strideC) {
    int batch = blockIdx.z;
    A  += (long)batch * strideA;
    Bm += (long)batch * strideB;
    C  += (long)batch * strideC;
    const int BM = 64, BN = 64, BK = 16;
    __shared__ float As[BK][BM + 1];
    __shared__ float Bs[BK][BN + 1];
    int tid = threadIdx.x;
    int m0 = blockIdx.y * BM, n0 = blockIdx.x * BN;
    int tx = tid & 15, ty = tid >> 4;
    float acc[4][4] = {};
    for (int k0 = 0; k0 < K; k0 += BK) {
        {
            int m = tid >> 2, kk = (tid & 3) * 4;
            int gm = m0 + m;
#pragma unroll
            for (int q = 0; q < 4; q++) {
                int gk = k0 + kk + q;
                float x = (gm < M && gk < K) ? A[(long)gm * lda + gk] : 0.f;
                As[kk + q][m] = x;
            }
        }
        if (!BT) {
            int kk = tid >> 4, n = (tid & 15) * 4;
            int gk = k0 + kk;
#pragma unroll
            for (int q = 0; q < 4; q++) {
                int gn = n0 + n + q;
                float x = (gk < K && gn < N) ? Bm[(long)gk * ldb + gn] : 0.f;
                Bs[kk][n + q] = x;
            }
        } else {
            int n = tid >> 2, kk = (tid & 3) * 4;
            int gn = n0 + n;
#pragma unroll
            for (int q = 0; q < 4; q++) {
                int gk = k0 + kk + q;
                float x = (gn < N && gk < K) ? Bm[(long)gn * ldb + gk] : 0.f;
                Bs[kk + q][n] = x;
            }
        }
        __syncthreads();
#pragma unroll
        for (int kk = 0; kk < BK; kk++) {
            float a[4], bv[4];
#pragma unroll
            for (int q = 0; q < 4; q++) a[q] = As[kk][ty * 4 + q];
#pragma unroll
            for (int q = 0; q < 4; q++) bv[q] = Bs[kk][tx * 4 + q];
#pragma unroll
            for (int i = 0; i < 4; i++)
#pragma unroll
                for (int j = 0; j < 4; j++)
                    acc[i][j] += a[i] * bv[j];
        }
        __syncthreads();
    }
#pragma unroll
    for (int i = 0; i < 4; i++) {
        int gm = m0 + ty * 4 + i;
        if (gm >= M) continue;
#pragma unroll
        for (int j = 0; j < 4; j++) {
            int gn = n0 + tx * 4 + j;
            if (gn >= N) continue;
            float v = acc[i][j];
            if (LEAKY) v = (v >= 0.f) ? v : 0.01f * v;
            C[(long)gm * ldc + gn] = v;
        }
    }
}

__global__ void mean_plain_kernel(const float* __restrict__ enc,
                                  const int* __restrict__ event_type,
                                  const float* __restrict__ pope,
                                  float* __restrict__ ue) {
    int b = blockIdx.x, d = threadIdx.x;
    float s1 = 0.f, s2 = 0.f;
    for (int l = 0; l < L_; l++) {
        s1 += enc[((long)b * L_ + l) * D_ + d];
        int et = event_type[b * L_ + l];
        float np = (et != 0) ? 1.0f : 0.0f;
        s2 += pope[(long)et * D_ + d] * np;
    }
    ue[b * (2 * D_) + d]      = s1 / (float)L_;
    ue[b * (2 * D_) + D_ + d] = (s2 / (float)L_) * BETA1;
}

__global__ void adj_kernel_f32(const int* __restrict__ event_type,
                               const float* __restrict__ A,
                               const float* __restrict__ diag,
                               float* __restrict__ adj) {
    int b = blockIdx.y;
    int i = blockIdx.x;
    int j = threadIdx.x;
    __shared__ int sidx[L_];
    __shared__ float sdiag[L_];
    if (j < L_) {
        sidx[j]  = event_type[b * L_ + j] - 1;
        sdiag[j] = diag[b * L_ + j];
    }
    __syncthreads();
    if (j >= L_) return;
    long row = (long)event_type[b * L_ + i] - 1;
    adj[((long)b * L_ + i) * L_ + j] = A[row * NT_ + sidx[j]] + sdiag[j];
}

__global__ void normtanh_kernel(float* __restrict__ pred) {
    int b = blockIdx.x;
    int t = threadIdx.x;
    float* row = pred + (long)b * NT_;
    float sq = 0.f;
    for (int i = t; i < NT_; i += 256) { float v = row[i]; sq += v * v; }
    for (int off = 32; off > 0; off >>= 1) sq += __shfl_down(sq, off, 64);
    __shared__ float s[4];
    int wid = t >> 6, lane = t & 63;
    if (lane == 0) s[wid] = sq;
    __syncthreads();
    float n = sqrtf(s[0] + s[1] + s[2] + s[3]);
    n = fmaxf(n, 1e-5f);
    float inv = 1.f / n;
    for (int i = t; i < NT_; i += 256) row[i] = tanhf(row[i] * inv);
}

extern "C" void kernel_launch(void* const* d_in, const int* in_sizes, int n_in,
                              void* d_out, int out_size, void* d_ws, size_t ws_size,
                              hipStream_t stream) {
    const int*   user_id    = (const int*)d_in[0];
    const int*   event_type = (const int*)d_in[1];
    const float* A          = (const float*)d_in[2];
    const float* pope       = (const float*)d_in[3];
    const float* E          = (const float*)d_in[4];
    const float* U          = (const float*)d_in[5];
    const float* W          = (const float*)d_in[6];

    float* out  = (float*)d_out;
    float* pred = out;                               // B*NT
    float* ue   = out + (long)B_ * NT_;              // B*2D
    float* pop  = ue  + (long)B_ * 2 * D_;           // B*L*D

    // ---- fast-path workspace carve ----
    char* w = (char*)d_ws;
    auto carve = [&](size_t bytes) { char* p = w; w += (bytes + 255) & ~(size_t)255; return p; };
    unsigned int* amax = (unsigned int*)carve(64);
    _Float16* adjH  = (_Float16*)carve((size_t)B_ * L_ * L_ * 2);
    _Float16* adjL  = (_Float16*)carve((size_t)B_ * L_ * L_ * 2);
    _Float16* tmpH  = (_Float16*)carve((size_t)B_ * L_ * D_ * 2);
    _Float16* tmpL  = (_Float16*)carve((size_t)B_ * L_ * D_ * 2);
    float*    encF  = (float*)carve((size_t)B_ * L_ * D_ * 4);
    _Float16* WTh   = (_Float16*)carve((size_t)NL_ * D_ * D_ * 2);
    _Float16* WTl   = (_Float16*)carve((size_t)NL_ * D_ * D_ * 2);
    _Float16* ETh   = (_Float16*)carve((size_t)NT_ * D_ * 2);
    _Float16* ETl   = (_Float16*)carve((size_t)NT_ * D_ * 2);
    _Float16* ueh   = (_Float16*)carve((size_t)B_ * D_ * 2);
    _Float16* uel   = (_Float16*)carve((size_t)B_ * D_ * 2);
    float*    unorm = (float*)carve((size_t)B_ * D_ * 4);
    float*    diag  = (float*)carve((size_t)B_ * L_ * 4);
    size_t needed = (size_t)(w - (char*)d_ws);

    if (ws_size >= needed) {
        // ================= fast path =================
        user_norm_kernel<<<B_, 256, 0, stream>>>(user_id, U, unorm, amax);
        enc0pop_kernel<<<1280, 256, 0, stream>>>(event_type, E, pope, unorm, encF, pop, amax);
        diag_kernel<<<(B_ * L_ + 255) / 256, 256, 0, stream>>>(event_type, A, diag);
        adj_split_kernel<<<dim3(50, B_), 256, 0, stream>>>(event_type, A, diag, adjH, adjL);
        wsplit_kernel<<<dim3(4, 4, NL_), 256, 0, stream>>>(W, WTh, WTl);
        esplit_kernel<<<NT_ * D_ / 1024, 256, 0, stream>>>(E, ETh, ETl);

        for (int i = 0; i < NL_; i++) {
            gemm1_kernel<<<dim3(2, 2, B_), 256, 0, stream>>>(
                adjH, adjL, encF, tmpH, tmpL, amax, i);
            gemm2_kernel<<<dim3(2, B_ * L_ / 128), 256, 0, stream>>>(
                tmpH, tmpL, WTh + (long)i * D_ * D_, WTl + (long)i * D_ * D_,
                encF, amax + i + 1);
        }

        mean_fused_kernel<<<B_, 1024, 0, stream>>>(encF, event_type, pope, amax, ue, ueh, uel);
        pred_mfma_kernel<<<(NT_ + 63) / 64, 256, 0, stream>>>(ueh, uel, ETh, ETl, pred);
        normtanh2_kernel<<<B_, 1024, 0, stream>>>(pred);
    } else {
        // ================= fallback: f32 path =================
        float* ws0   = (float*)d_ws;
        float* uno   = ws0;
        float* dia   = uno + B_ * D_;
        float* adjF  = dia + B_ * L_;
        float* encA2 = adjF + (long)B_ * L_ * L_;
        float* encB2 = encA2 + (long)B_ * L_ * D_;
        float* tmp   = pop;

        user_norm_kernel<<<B_, 256, 0, stream>>>(user_id, U, uno, (unsigned int*)dia);
        enc0_kernel<<<1280, 256, 0, stream>>>(event_type, E, uno, encA2);
        diag_kernel<<<(B_ * L_ + 255) / 256, 256, 0, stream>>>(event_type, A, dia);
        adj_kernel_f32<<<dim3(L_, B_), 256, 0, stream>>>(event_type, A, dia, adjF);

        float* cur = encA2; float* nxt = encB2;
        for (int i = 0; i < NL_; i++) {
            dim3 g1((D_ + 63) / 64, (L_ + 63) / 64, B_);
            gemm_kernel<false, false><<<g1, 256, 0, stream>>>(
                adjF, cur, tmp, L_, D_, L_, L_, D_, D_,
                (long)L_ * L_, (long)L_ * D_, (long)L_ * D_);
            dim3 g2((D_ + 63) / 64, (B_ * L_ + 63) / 64, 1);
            gemm_kernel<false, true><<<g2, 256, 0, stream>>>(
                tmp, W + (long)i * D_ * D_, nxt, B_ * L_, D_, D_, D_, D_, D_, 0, 0, 0);
            float* t = cur; cur = nxt; nxt = t;
        }
        pop_kernel<<<B_ * L_, 256, 0, stream>>>(event_type, pope, pop);
        mean_plain_kernel<<<B_, 256, 0, stream>>>(cur, event_type, pope, ue);

        dim3 g3((NT_ + 63) / 64, (B_ + 63) / 64, 1);
        gemm_kernel<true, false><<<g3, 256, 0, stream>>>(
            ue, E + D_, pred, B_, NT_, D_, 2 * D_, D_, NT_, 0, 0, 0);
        normtanh_kernel<<<B_, 256, 0, stream>>>(pred);
    }
}

// Round 20
// 357.026 us; speedup vs baseline: 5.0039x; 1.0917x over previous
//
#include <hip/hip_runtime.h>
#include <math.h>

#define B_ 128
#define L_ 200
#define D_ 256
#define NT_ 10000
#define NL_ 4
#define BETA1 0.1f

typedef _Float16 f16x8 __attribute__((ext_vector_type(8)));
typedef _Float16 f16x4 __attribute__((ext_vector_type(4)));
typedef float f32x4 __attribute__((ext_vector_type(4)));

struct HL { _Float16 h, l; };
__device__ __forceinline__ HL split2v(float v) {
    HL r;
    r.h = (_Float16)v;
    r.l = (_Float16)(v - (float)r.h);
    return r;
}

__device__ __forceinline__ float getscale(const unsigned int* amax, int i, int extra) {
    float am = fmaxf(__uint_as_float(amax[i]), 1e-30f);
    return scalbnf(1.f, 6 - ilogbf(am) - extra);
}

// ---------------- user l2norm (+ amax zero-init in block 0) ----------------
__global__ void user_norm_kernel(const int* __restrict__ user_id,
                                 const float* __restrict__ user_emb_w,
                                 float* __restrict__ unorm,
                                 unsigned int* __restrict__ amax) {
    int b = blockIdx.x;
    int d = threadIdx.x; // 256
    if (b == 0 && d < 16) amax[d] = 0u;
    int uid = user_id[b];
    float v = user_emb_w[(long)uid * D_ + d];
    float sq = v * v;
    for (int off = 32; off > 0; off >>= 1) sq += __shfl_down(sq, off, 64);
    __shared__ float s[4];
    int wid = d >> 6, lane = d & 63;
    if (lane == 0) s[wid] = sq;
    __syncthreads();
    float n = sqrtf(s[0] + s[1] + s[2] + s[3]);
    n = fmaxf(n, 1e-12f);
    unorm[b * D_ + d] = v / n;
}

// ---------------- enc0 + pop fused; absmax one atomic per block ----------------
__global__ void enc0pop_kernel(const int* __restrict__ event_type,
                               const float* __restrict__ E,
                               const float* __restrict__ pope,
                               const float* __restrict__ unorm,
                               float* __restrict__ encF,
                               float* __restrict__ pop_out,
                               unsigned int* __restrict__ amax) {
    int d = threadIdx.x;           // 256
    float m = 0.f;
    for (int bl = blockIdx.x; bl < B_ * L_; bl += gridDim.x) {
        int b = bl / L_;
        int et = event_type[bl];
        float e = E[(long)et * D_ + d];
        float sg = (e > 0.f) ? 1.f : ((e < 0.f) ? -1.f : 0.f);
        float u = unorm[b * D_ + d];
        float v = e + sg * u;
        encF[(long)bl * D_ + d] = v;
        m = fmaxf(m, fabsf(v));
        pop_out[(long)bl * D_ + d] = (et != 0) ? pope[(long)et * D_ + d] : 0.f;
    }
    for (int off = 32; off > 0; off >>= 1) m = fmaxf(m, __shfl_down(m, off, 64));
    __shared__ float sm[4];
    int wid = d >> 6, lane = d & 63;
    if (lane == 0) sm[wid] = m;
    __syncthreads();
    if (d == 0)
        atomicMax(amax, __float_as_uint(fmaxf(fmaxf(sm[0], sm[1]), fmaxf(sm[2], sm[3]))));
}

// ---------------- diag[b,j] = A[idx_j, idx_j] ----------------
__global__ void diag_kernel(const int* __restrict__ event_type,
                            const float* __restrict__ A,
                            float* __restrict__ diag) {
    int i = blockIdx.x * blockDim.x + threadIdx.x;
    if (i >= B_ * L_) return;
    long idx = (long)event_type[i] - 1;
    diag[i] = A[idx * NT_ + idx];
}

// ---------------- adj split: 4 rows/block (staging amortized, ILP 4) ----------------
__global__ void adj_split_kernel(const int* __restrict__ event_type,
                                 const float* __restrict__ A,
                                 const float* __restrict__ diag,
                                 _Float16* __restrict__ adjH,
                                 _Float16* __restrict__ adjL) {
    int b = blockIdx.y;
    int i0 = blockIdx.x * 4;        // 50 blocks x 4 rows
    int j = threadIdx.x;            // 256 threads, j < L_ active
    __shared__ int sidx[L_];
    __shared__ float sdiag[L_];
    if (j < L_) {
        sidx[j]  = event_type[b * L_ + j] - 1;
        sdiag[j] = diag[b * L_ + j];
    }
    __syncthreads();
    if (j >= L_) return;
    float dj = sdiag[j];
    int cj = sidx[j];
#pragma unroll
    for (int r = 0; r < 4; r++) {
        int i = i0 + r;
        float v = A[(long)sidx[i] * NT_ + cj] + dj;
        HL s = split2v(v);
        long o = ((long)b * L_ + i) * L_ + j;
        adjH[o] = s.h; adjL[o] = s.l;
    }
}

// ---------------- W^T split ----------------
__global__ void wsplit_kernel(const float* __restrict__ W,
                              _Float16* __restrict__ WTh,
                              _Float16* __restrict__ WTl) {
    int layer = blockIdx.z;
    int k0 = blockIdx.y * 64, n0 = blockIdx.x * 64;
    const float* Wl = W + (long)layer * D_ * D_;
    __shared__ float t[64][65];
    int tid = threadIdx.x;
    for (int i = 0; i < 16; i++) {
        int idx = i * 256 + tid;
        int k = idx >> 6, n = idx & 63;
        t[k][n] = Wl[(long)(k0 + k) * D_ + n0 + n];
    }
    __syncthreads();
    for (int i = 0; i < 16; i++) {
        int idx = i * 256 + tid;
        int n = idx >> 6, k = idx & 63;
        float v = t[k][n];
        long o = (long)layer * D_ * D_ + (long)(n0 + n) * D_ + (k0 + k);
        HL r = split2v(v);
        WTh[o] = r.h; WTl[o] = r.l;
    }
}

// ---------------- E[1:] split: [n][k] f16 h/l ----------------
__global__ void esplit_kernel(const float* __restrict__ E,
                              _Float16* __restrict__ ETh,
                              _Float16* __restrict__ ETl) {
    long f = ((long)blockIdx.x * 256 + threadIdx.x) * 4;
    float4 v = *(const float4*)(E + D_ + f);
    f16x4 h, l;
    HL r0 = split2v(v.x); h[0] = r0.h; l[0] = r0.l;
    HL r1 = split2v(v.y); h[1] = r1.h; l[1] = r1.l;
    HL r2 = split2v(v.z); h[2] = r2.h; l[2] = r2.l;
    HL r3 = split2v(v.w); h[3] = r3.h; l[3] = r3.l;
    *(f16x4*)(ETh + f) = h;
    *(f16x4*)(ETl + f) = l;
}

// ---------------- gemm1: tmp = adj @ enc (two-phase B staging; 3 waves/EU) ------
__global__ __launch_bounds__(256, 3) void gemm1_kernel(
    const _Float16* __restrict__ adjH, const _Float16* __restrict__ adjL,
    const float* __restrict__ encF,
    _Float16* __restrict__ tmpH, _Float16* __restrict__ tmpL,
    const unsigned int* __restrict__ amax, int layer) {
    int b = blockIdx.z;
    const _Float16* Ah = adjH + (long)b * L_ * L_;
    const _Float16* Al = adjL + (long)b * L_ * L_;
    const float*    Bf = encF + (long)b * L_ * D_;
    int m0 = blockIdx.y * 128, n0 = blockIdx.x * 128;
    int tid = threadIdx.x, lane = tid & 63, wid = tid >> 6;
    int wr = wid >> 1, wc = wid & 1;
    float scale = getscale(amax, layer, 0);

    __shared__ _Float16 sAh[128][40], sAl[128][40];
    __shared__ _Float16 sBh[128][40], sBl[128][40];

    f32x4 acc[4][4] = {};
    int fr = lane & 15, kb = (lane >> 4) * 8, fq = lane >> 4;

    for (int k0 = 0; k0 < L_; k0 += 32) {
        // ---- phase 1: issue ALL global loads (A 2x16B, B 16 f32) before any convert ----
        f16x8 vAh[2], vAl[2];
#pragma unroll
        for (int c = 0; c < 2; c++) {
            int idx = c * 256 + tid;
            int row = idx >> 2, kq = (idx & 3) * 8;
            int gk = k0 + kq;
            f16x8 vh = {}, vl = {};
            if (m0 + row < L_ && gk < L_) {
                long o = (long)(m0 + row) * L_ + gk;
                vh = *(const f16x8*)(Ah + o);
                vl = *(const f16x8*)(Al + o);
            }
            vAh[c] = vh; vAl[c] = vl;
        }
        float vv[2][8];
#pragma unroll
        for (int q2 = 0; q2 < 2; q2++) {
            int item = q2 * 256 + tid;
            int n = item & 127;
            int oct = item >> 7;          // 0..3
            int gk0 = k0 + oct * 8;
#pragma unroll
            for (int q = 0; q < 8; q++) {
                int gk = gk0 + q;
                vv[q2][q] = (gk < L_) ? Bf[(long)gk * D_ + n0 + n] : 0.f;
            }
        }
        // ---- phase 2: convert + LDS writes ----
#pragma unroll
        for (int c = 0; c < 2; c++) {
            int idx = c * 256 + tid;
            int row = idx >> 2, kq = (idx & 3) * 8;
            *(f16x8*)&sAh[row][kq] = vAh[c];
            *(f16x8*)&sAl[row][kq] = vAl[c];
        }
#pragma unroll
        for (int q2 = 0; q2 < 2; q2++) {
            int item = q2 * 256 + tid;
            int n = item & 127;
            int oct = item >> 7;
            f16x8 h, l;
#pragma unroll
            for (int q = 0; q < 8; q++) {
                HL r = split2v(vv[q2][q] * scale);
                h[q] = r.h; l[q] = r.l;
            }
            *(f16x8*)&sBh[n][oct * 8] = h;
            *(f16x8*)&sBl[n][oct * 8] = l;
        }
        __syncthreads();

        f16x8 fbh[4], fbl[4];
#pragma unroll
        for (int n = 0; n < 4; n++) {
            int rB = wc * 64 + n * 16 + fr;
            fbh[n] = *(const f16x8*)&sBh[rB][kb];
            fbl[n] = *(const f16x8*)&sBl[rB][kb];
        }
#pragma unroll
        for (int m = 0; m < 4; m++) {
            int rA = wr * 64 + m * 16 + fr;
            f16x8 fah = *(const f16x8*)&sAh[rA][kb];
            f16x8 fal = *(const f16x8*)&sAl[rA][kb];
#pragma unroll
            for (int n = 0; n < 4; n++) {
                acc[m][n] = __builtin_amdgcn_mfma_f32_16x16x32_f16(fah, fbh[n], acc[m][n], 0, 0, 0);
                acc[m][n] = __builtin_amdgcn_mfma_f32_16x16x32_f16(fah, fbl[n], acc[m][n], 0, 0, 0);
                acc[m][n] = __builtin_amdgcn_mfma_f32_16x16x32_f16(fal, fbh[n], acc[m][n], 0, 0, 0);
            }
        }
        __syncthreads();
    }

    _Float16* Ch = tmpH + (long)b * L_ * D_;
    _Float16* Cl = tmpL + (long)b * L_ * D_;
#pragma unroll
    for (int m = 0; m < 4; m++)
#pragma unroll
        for (int n = 0; n < 4; n++)
#pragma unroll
            for (int r = 0; r < 4; r++) {
                int row = m0 + wr * 64 + m * 16 + fq * 4 + r;
                int col = n0 + wc * 64 + n * 16 + fr;
                if (row < L_) {
                    HL s = split2v(acc[m][n][r]);
                    long o = (long)row * D_ + col;
                    Ch[o] = s.h; Cl[o] = s.l;
                }
            }
}

// ---------------- gemm2: encF = leaky(tmp @ W), absmax (two-phase staging) -------
__global__ __launch_bounds__(256) void gemm2_kernel(
    const _Float16* __restrict__ Ah, const _Float16* __restrict__ Al,
    const _Float16* __restrict__ Bh, const _Float16* __restrict__ Bl,
    float* __restrict__ Cf, unsigned int* __restrict__ amax) {
    int m0 = blockIdx.y * 128, n0 = blockIdx.x * 128;
    int tid = threadIdx.x, lane = tid & 63, wid = tid >> 6;
    int wr = wid >> 1, wc = wid & 1;
    __shared__ _Float16 sAh[128][40], sAl[128][40];
    __shared__ _Float16 sBh[128][40], sBl[128][40];
    __shared__ float sRed[4];
    f32x4 acc[4][4] = {};
    int fr = lane & 15, kb = (lane >> 4) * 8, fq = lane >> 4;

    for (int k0 = 0; k0 < D_; k0 += 32) {
        // phase 1: all loads
        f16x8 vAh[2], vAl[2], vBh[2], vBl[2];
#pragma unroll
        for (int c = 0; c < 2; c++) {
            int idx = c * 256 + tid;
            int row = idx >> 2, kq = (idx & 3) * 8, gk = k0 + kq;
            long oa = (long)(m0 + row) * D_ + gk;
            vAh[c] = *(const f16x8*)(Ah + oa);
            vAl[c] = *(const f16x8*)(Al + oa);
            long ob = (long)(n0 + row) * D_ + gk;
            vBh[c] = *(const f16x8*)(Bh + ob);
            vBl[c] = *(const f16x8*)(Bl + ob);
        }
        // phase 2: LDS writes
#pragma unroll
        for (int c = 0; c < 2; c++) {
            int idx = c * 256 + tid;
            int row = idx >> 2, kq = (idx & 3) * 8;
            *(f16x8*)&sAh[row][kq] = vAh[c];
            *(f16x8*)&sAl[row][kq] = vAl[c];
            *(f16x8*)&sBh[row][kq] = vBh[c];
            *(f16x8*)&sBl[row][kq] = vBl[c];
        }
        __syncthreads();
        f16x8 fbh[4], fbl[4];
#pragma unroll
        for (int n = 0; n < 4; n++) {
            int rB = wc * 64 + n * 16 + fr;
            fbh[n] = *(const f16x8*)&sBh[rB][kb];
            fbl[n] = *(const f16x8*)&sBl[rB][kb];
        }
#pragma unroll
        for (int m = 0; m < 4; m++) {
            int rA = wr * 64 + m * 16 + fr;
            f16x8 fah = *(const f16x8*)&sAh[rA][kb];
            f16x8 fal = *(const f16x8*)&sAl[rA][kb];
#pragma unroll
            for (int n = 0; n < 4; n++) {
                acc[m][n] = __builtin_amdgcn_mfma_f32_16x16x32_f16(fah, fbh[n], acc[m][n], 0, 0, 0);
                acc[m][n] = __builtin_amdgcn_mfma_f32_16x16x32_f16(fah, fbl[n], acc[m][n], 0, 0, 0);
                acc[m][n] = __builtin_amdgcn_mfma_f32_16x16x32_f16(fal, fbh[n], acc[m][n], 0, 0, 0);
            }
        }
        __syncthreads();
    }

    float tmax = 0.f;
#pragma unroll
    for (int m = 0; m < 4; m++)
#pragma unroll
        for (int n = 0; n < 4; n++)
#pragma unroll
            for (int r = 0; r < 4; r++) {
                int row = m0 + wr * 64 + m * 16 + fq * 4 + r;
                int col = n0 + wc * 64 + n * 16 + fr;
                float v = acc[m][n][r];
                v = (v >= 0.f) ? v : 0.01f * v;
                Cf[(long)row * D_ + col] = v;
                tmax = fmaxf(tmax, fabsf(v));
            }
    for (int off = 32; off > 0; off >>= 1) tmax = fmaxf(tmax, __shfl_down(tmax, off, 64));
    if (lane == 0) sRed[wid] = tmax;
    __syncthreads();
    if (tid == 0)
        atomicMax(amax, __float_as_uint(fmaxf(fmaxf(sRed[0], sRed[1]), fmaxf(sRed[2], sRed[3]))));
}

// ---------------- mean + ue + uesplit fused, 1024 thr (4 l-chunks parallel) -----
__global__ __launch_bounds__(1024) void mean_fused_kernel(
    const float* __restrict__ encF,
    const int* __restrict__ event_type,
    const float* __restrict__ pope,
    const unsigned int* __restrict__ amax,
    float* __restrict__ ue,
    _Float16* __restrict__ ueh,
    _Float16* __restrict__ uel) {
    int b = blockIdx.x, tid = threadIdx.x;
    int c = tid >> 8, d = tid & 255;
    float s1 = 0.f, s2 = 0.f;
    int l0 = c * 50;
    for (int l = l0; l < l0 + 50; l++) {
        s1 += encF[((long)b * L_ + l) * D_ + d];
        int et = event_type[b * L_ + l];
        s2 += (et != 0) ? pope[(long)et * D_ + d] : 0.f;
    }
    __shared__ float red1[4][256], red2[4][256];
    red1[c][d] = s1;
    red2[c][d] = s2;
    __syncthreads();
    if (c == 0) {
        s1 = red1[0][d] + red1[1][d] + red1[2][d] + red1[3][d];
        s2 = red2[0][d] + red2[1][d] + red2[2][d] + red2[3][d];
        float S = 1.f;
        for (int i = 0; i < NL_; i++) S *= getscale(amax, i, 0);
        ue[b * 2 * D_ + d]      = s1 / (float)L_ / S;
        ue[b * 2 * D_ + D_ + d] = s2 * (BETA1 / (float)L_);
        float sc = getscale(amax, NL_, 8);
        HL r = split2v(s1 * sc);
        ueh[b * D_ + d] = r.h;
        uel[b * D_ + d] = r.l;
    }
}

// ---------------- pred = ue_scaled @ E[1:]^T (two-phase staging) ----------------
__global__ __launch_bounds__(256) void pred_mfma_kernel(
    const _Float16* __restrict__ Ah, const _Float16* __restrict__ Al,
    const _Float16* __restrict__ Bh, const _Float16* __restrict__ Bl,
    float* __restrict__ Cf) {
    int n0 = blockIdx.x * 64;
    int tid = threadIdx.x, lane = tid & 63, wid = tid >> 6;
    int wr = wid >> 1, wc = wid & 1;
    __shared__ _Float16 sAh[128][40], sAl[128][40];
    __shared__ _Float16 sBh[64][40], sBl[64][40];
    f32x4 acc[4][2] = {};
    int fr = lane & 15, kb = (lane >> 4) * 8, fq = lane >> 4;

    for (int k0 = 0; k0 < D_; k0 += 32) {
        // phase 1: all loads
        f16x8 vAh[2], vAl[2], vBh, vBl;
#pragma unroll
        for (int c = 0; c < 2; c++) {
            int idx = c * 256 + tid;
            int row = idx >> 2, kq = (idx & 3) * 8, gk = k0 + kq;
            long oa = (long)row * D_ + gk;
            vAh[c] = *(const f16x8*)(Ah + oa);
            vAl[c] = *(const f16x8*)(Al + oa);
        }
        {
            int row = tid >> 2, kq = (tid & 3) * 8, gk = k0 + kq;
            f16x8 wh = {}, wl = {};
            if (n0 + row < NT_) {
                long ob = (long)(n0 + row) * D_ + gk;
                wh = *(const f16x8*)(Bh + ob);
                wl = *(const f16x8*)(Bl + ob);
            }
            vBh = wh; vBl = wl;
        }
        // phase 2: LDS writes
#pragma unroll
        for (int c = 0; c < 2; c++) {
            int idx = c * 256 + tid;
            int row = idx >> 2, kq = (idx & 3) * 8;
            *(f16x8*)&sAh[row][kq] = vAh[c];
            *(f16x8*)&sAl[row][kq] = vAl[c];
        }
        {
            int row = tid >> 2, kq = (tid & 3) * 8;
            *(f16x8*)&sBh[row][kq] = vBh;
            *(f16x8*)&sBl[row][kq] = vBl;
        }
        __syncthreads();
        f16x8 fbh[2], fbl[2];
#pragma unroll
        for (int n = 0; n < 2; n++) {
            int rB = wc * 32 + n * 16 + fr;
            fbh[n] = *(const f16x8*)&sBh[rB][kb];
            fbl[n] = *(const f16x8*)&sBl[rB][kb];
        }
#pragma unroll
        for (int m = 0; m < 4; m++) {
            int rA = wr * 64 + m * 16 + fr;
            f16x8 fah = *(const f16x8*)&sAh[rA][kb];
            f16x8 fal = *(const f16x8*)&sAl[rA][kb];
#pragma unroll
            for (int n = 0; n < 2; n++) {
                acc[m][n] = __builtin_amdgcn_mfma_f32_16x16x32_f16(fah, fbh[n], acc[m][n], 0, 0, 0);
                acc[m][n] = __builtin_amdgcn_mfma_f32_16x16x32_f16(fah, fbl[n], acc[m][n], 0, 0, 0);
                acc[m][n] = __builtin_amdgcn_mfma_f32_16x16x32_f16(fal, fbh[n], acc[m][n], 0, 0, 0);
            }
        }
        __syncthreads();
    }
#pragma unroll
    for (int m = 0; m < 4; m++)
#pragma unroll
        for (int n = 0; n < 2; n++)
#pragma unroll
            for (int r = 0; r < 4; r++) {
                int row = wr * 64 + m * 16 + fq * 4 + r;
                int col = n0 + wc * 32 + n * 16 + fr;
                if (col < NT_)
                    Cf[(long)row * NT_ + col] = acc[m][n][r];
            }
}

// ---------------- norm + tanh fused, row in registers ----------------
__global__ void normtanh2_kernel(float* __restrict__ pred) {
    int b = blockIdx.x, t = threadIdx.x; // 1024
    float* row = pred + (long)b * NT_;
    float v[10];
    float sq = 0.f;
#pragma unroll
    for (int p = 0; p < 10; p++) {
        int i = p * 1024 + t;
        v[p] = (i < NT_) ? row[i] : 0.f;
        sq += v[p] * v[p];
    }
    for (int off = 32; off > 0; off >>= 1) sq += __shfl_down(sq, off, 64);
    __shared__ float s[16];
    if ((t & 63) == 0) s[t >> 6] = sq;
    __syncthreads();
    float n = 0.f;
    for (int i = 0; i < 16; i++) n += s[i];
    float inv = 1.f / fmaxf(sqrtf(n), 1e-5f);
#pragma unroll
    for (int p = 0; p < 10; p++) {
        int i = p * 1024 + t;
        if (i < NT_) row[i] = tanhf(v[p] * inv);
    }
}

// ================= fallback f32 path kernels =================
__global__ void enc0_kernel(const int* __restrict__ event_type,
                            const float* __restrict__ E,
                            const float* __restrict__ unorm,
                            float* __restrict__ encF) {
    int d = threadIdx.x;
    for (int bl = blockIdx.x; bl < B_ * L_; bl += gridDim.x) {
        int b = bl / L_;
        int et = event_type[bl];
        float e = E[(long)et * D_ + d];
        float sg = (e > 0.f) ? 1.f : ((e < 0.f) ? -1.f : 0.f);
        float u = unorm[b * D_ + d];
        encF[(long)bl * D_ + d] = e + sg * u;
    }
}

__global__ void pop_kernel(const int* __restrict__ event_type,
                           const float* __restrict__ pope,
                           float* __restrict__ pop_out) {
    int bl = blockIdx.x;
    int d = threadIdx.x;
    int et = event_type[bl];
    float np = (et != 0) ? 1.0f : 0.0f;
    pop_out[(long)bl * D_ + d] = pope[(long)et * D_ + d] * np;
}

template <bool BT, bool LEAKY>
__global__ void gemm_kernel(const float* __restrict__ A,
                            const float* __restrict__ Bm,
                            float* __restrict__ C,
                            int M, int N, int K, int lda, int ldb, int ldc,
                            long strideA, long strideB, long strideC) {
    int batch = blockIdx.z;
    A  += (long)batch * strideA;
    Bm += (long)batch * strideB;
    C  += (long)batch * strideC;
    const int BM = 64, BN = 64, BK = 16;
    __shared__ float As[BK][BM + 1];
    __shared__ float Bs[BK][BN + 1];
    int tid = threadIdx.x;
    int m0 = blockIdx.y * BM, n0 = blockIdx.x * BN;
    int tx = tid & 15, ty = tid >> 4;
    float acc[4][4] = {};
    for (int k0 = 0; k0 < K; k0 += BK) {
        {
            int m = tid >> 2, kk = (tid & 3) * 4;
            int gm = m0 + m;
#pragma unroll
            for (int q = 0; q < 4; q++) {
                int gk = k0 + kk + q;
                float x = (gm < M && gk < K) ? A[(long)gm * lda + gk] : 0.f;
                As[kk + q][m] = x;
            }
        }
        if (!BT) {
            int kk = tid >> 4, n = (tid & 15) * 4;
            int gk = k0 + kk;
#pragma unroll
            for (int q = 0; q < 4; q++) {
                int gn = n0 + n + q;
                float x = (gk < K && gn < N) ? Bm[(long)gk * ldb + gn] : 0.f;
                Bs[kk][n + q] = x;
            }
        } else {
            int n = tid >> 2, kk = (tid & 3) * 4;
            int gn = n0 + n;
#pragma unroll
            for (int q = 0; q < 4; q++) {
                int gk = k0 + kk + q;
                float x = (gn < N && gk < K) ? Bm[(long)gn * ldb + gk] : 0.f;
                Bs[kk + q][n] = x;
            }
        }
        __syncthreads();
#pragma unroll
        for (int kk = 0; kk < BK; kk++) {
            float a[4], bv[4];
#pragma unroll
            for (int q = 0; q < 4; q++) a[q] = As[kk][ty * 4 + q];
#pragma unroll
            for (int q = 0; q < 4; q++) bv[q] = Bs[kk][tx * 4 + q];
#pragma unroll
            for (int i = 0; i < 4; i++)
#pragma unroll
                for (int j = 0; j < 4; j++)
                    acc[i][j] += a[i] * bv[j];
        }
        __syncthreads();
    }
#pragma unroll
    for (int i = 0; i < 4; i++) {
        int gm = m0 + ty * 4 + i;
        if (gm >= M) continue;
#pragma unroll
        for (int j = 0; j < 4; j++) {
            int gn = n0 + tx * 4 + j;
            if (gn >= N) continue;
            float v = acc[i][j];
            if (LEAKY) v = (v >= 0.f) ? v : 0.01f * v;
            C[(long)gm * ldc + gn] = v;
        }
    }
}

__global__ void mean_plain_kernel(const float* __restrict__ enc,
                                  const int* __restrict__ event_type,
                                  const float* __restrict__ pope,
                                  float* __restrict__ ue) {
    int b = blockIdx.x, d = threadIdx.x;
    float s1 = 0.f, s2 = 0.f;
    for (int l = 0; l < L_; l++) {
        s1 += enc[((long)b * L_ + l) * D_ + d];
        int et = event_type[b * L_ + l];
        float np = (et != 0) ? 1.0f : 0.0f;
        s2 += pope[(long)et * D_ + d] * np;
    }
    ue[b * (2 * D_) + d]      = s1 / (float)L_;
    ue[b * (2 * D_) + D_ + d] = (s2 / (float)L_) * BETA1;
}

__global__ void adj_kernel_f32(const int* __restrict__ event_type,
                               const float* __restrict__ A,
                               const float* __restrict__ diag,
                               float* __restrict__ adj) {
    int b = blockIdx.y;
    int i = blockIdx.x;
    int j = threadIdx.x;
    __shared__ int sidx[L_];
    __shared__ float sdiag[L_];
    if (j < L_) {
        sidx[j]  = event_type[b * L_ + j] - 1;
        sdiag[j] = diag[b * L_ + j];
    }
    __syncthreads();
    if (j >= L_) return;
    long row = (long)event_type[b * L_ + i] - 1;
    adj[((long)b * L_ + i) * L_ + j] = A[row * NT_ + sidx[j]] + sdiag[j];
}

__global__ void normtanh_kernel(float* __restrict__ pred) {
    int b = blockIdx.x;
    int t = threadIdx.x;
    float* row = pred + (long)b * NT_;
    float sq = 0.f;
    for (int i = t; i < NT_; i += 256) { float v = row[i]; sq += v * v; }
    for (int off = 32; off > 0; off >>= 1) sq += __shfl_down(sq, off, 64);
    __shared__ float s[4];
    int wid = t >> 6, lane = t & 63;
    if (lane == 0) s[wid] = sq;
    __syncthreads();
    float n = sqrtf(s[0] + s[1] + s[2] + s[3]);
    n = fmaxf(n, 1e-5f);
    float inv = 1.f / n;
    for (int i = t; i < NT_; i += 256) row[i] = tanhf(row[i] * inv);
}

extern "C" void kernel_launch(void* const* d_in, const int* in_sizes, int n_in,
                              void* d_out, int out_size, void* d_ws, size_t ws_size,
                              hipStream_t stream) {
    const int*   user_id    = (const int*)d_in[0];
    const int*   event_type = (const int*)d_in[1];
    const float* A          = (const float*)d_in[2];
    const float* pope       = (const float*)d_in[3];
    const float* E          = (const float*)d_in[4];
    const float* U          = (const float*)d_in[5];
    const float* W          = (const float*)d_in[6];

    float* out  = (float*)d_out;
    float* pred = out;                               // B*NT
    float* ue   = out + (long)B_ * NT_;              // B*2D
    float* pop  = ue  + (long)B_ * 2 * D_;           // B*L*D

    // ---- fast-path workspace carve ----
    char* w = (char*)d_ws;
    auto carve = [&](size_t bytes) { char* p = w; w += (bytes + 255) & ~(size_t)255; return p; };
    unsigned int* amax = (unsigned int*)carve(64);
    _Float16* adjH  = (_Float16*)carve((size_t)B_ * L_ * L_ * 2);
    _Float16* adjL  = (_Float16*)carve((size_t)B_ * L_ * L_ * 2);
    _Float16* tmpH  = (_Float16*)carve((size_t)B_ * L_ * D_ * 2);
    _Float16* tmpL  = (_Float16*)carve((size_t)B_ * L_ * D_ * 2);
    float*    encF  = (float*)carve((size_t)B_ * L_ * D_ * 4);
    _Float16* WTh   = (_Float16*)carve((size_t)NL_ * D_ * D_ * 2);
    _Float16* WTl   = (_Float16*)carve((size_t)NL_ * D_ * D_ * 2);
    _Float16* ETh   = (_Float16*)carve((size_t)NT_ * D_ * 2);
    _Float16* ETl   = (_Float16*)carve((size_t)NT_ * D_ * 2);
    _Float16* ueh   = (_Float16*)carve((size_t)B_ * D_ * 2);
    _Float16* uel   = (_Float16*)carve((size_t)B_ * D_ * 2);
    float*    unorm = (float*)carve((size_t)B_ * D_ * 4);
    float*    diag  = (float*)carve((size_t)B_ * L_ * 4);
    size_t needed = (size_t)(w - (char*)d_ws);

    if (ws_size >= needed) {
        // ================= fast path =================
        user_norm_kernel<<<B_, 256, 0, stream>>>(user_id, U, unorm, amax);
        enc0pop_kernel<<<1280, 256, 0, stream>>>(event_type, E, pope, unorm, encF, pop, amax);
        diag_kernel<<<(B_ * L_ + 255) / 256, 256, 0, stream>>>(event_type, A, diag);
        adj_split_kernel<<<dim3(50, B_), 256, 0, stream>>>(event_type, A, diag, adjH, adjL);
        wsplit_kernel<<<dim3(4, 4, NL_), 256, 0, stream>>>(W, WTh, WTl);
        esplit_kernel<<<NT_ * D_ / 1024, 256, 0, stream>>>(E, ETh, ETl);

        for (int i = 0; i < NL_; i++) {
            gemm1_kernel<<<dim3(2, 2, B_), 256, 0, stream>>>(
                adjH, adjL, encF, tmpH, tmpL, amax, i);
            gemm2_kernel<<<dim3(2, B_ * L_ / 128), 256, 0, stream>>>(
                tmpH, tmpL, WTh + (long)i * D_ * D_, WTl + (long)i * D_ * D_,
                encF, amax + i + 1);
        }

        mean_fused_kernel<<<B_, 1024, 0, stream>>>(encF, event_type, pope, amax, ue, ueh, uel);
        pred_mfma_kernel<<<(NT_ + 63) / 64, 256, 0, stream>>>(ueh, uel, ETh, ETl, pred);
        normtanh2_kernel<<<B_, 1024, 0, stream>>>(pred);
    } else {
        // ================= fallback: f32 path =================
        float* ws0   = (float*)d_ws;
        float* uno   = ws0;
        float* dia   = uno + B_ * D_;
        float* adjF  = dia + B_ * L_;
        float* encA2 = adjF + (long)B_ * L_ * L_;
        float* encB2 = encA2 + (long)B_ * L_ * D_;
        float* tmp   = pop;

        user_norm_kernel<<<B_, 256, 0, stream>>>(user_id, U, uno, (unsigned int*)dia);
        enc0_kernel<<<1280, 256, 0, stream>>>(event_type, E, uno, encA2);
        diag_kernel<<<(B_ * L_ + 255) / 256, 256, 0, stream>>>(event_type, A, dia);
        adj_kernel_f32<<<dim3(L_, B_), 256, 0, stream>>>(event_type, A, dia, adjF);

        float* cur = encA2; float* nxt = encB2;
        for (int i = 0; i < NL_; i++) {
            dim3 g1((D_ + 63) / 64, (L_ + 63) / 64, B_);
            gemm_kernel<false, false><<<g1, 256, 0, stream>>>(
                adjF, cur, tmp, L_, D_, L_, L_, D_, D_,
                (long)L_ * L_, (long)L_ * D_, (long)L_ * D_);
            dim3 g2((D_ + 63) / 64, (B_ * L_ + 63) / 64, 1);
            gemm_kernel<false, true><<<g2, 256, 0, stream>>>(
                tmp, W + (long)i * D_ * D_, nxt, B_ * L_, D_, D_, D_, D_, D_, 0, 0, 0);
            float* t = cur; cur = nxt; nxt = t;
        }
        pop_kernel<<<B_ * L_, 256, 0, stream>>>(event_type, pope, pop);
        mean_plain_kernel<<<B_, 256, 0, stream>>>(cur, event_type, pope, ue);

        dim3 g3((NT_ + 63) / 64, (B_ + 63) / 64, 1);
        gemm_kernel<true, false><<<g3, 256, 0, stream>>>(
            ue, E + D_, pred, B_, NT_, D_, 2 * D_, D_, NT_, 0, 0, 0);
        normtanh_kernel<<<B_, 256, 0, stream>>>(pred);
    }
}